// Round 10
// baseline (691.485 us; speedup 1.0000x reference)
//
#include <hip/hip_runtime.h>
#include <hip/hip_fp16.h>
#include <math.h>

// HeteroGNN: 2-layer bipartite single-head GAT (users<->badges).
// R10: CSR build de-latency-ized (R9: partition 72us was LDS-latency bound
// on the 8-step binary-search flush; refine+fine = extra 20MB RT):
//   1) k_partition: u16 bin side-array in LDS scatter -> flush is direct
//      index math (3 independent LDS reads), no dependent search chain.
//   2) k_sort2 replaces refine+bucket_fine: one 512-thr block per HALF
//      coarse bucket; within a coarse bucket the full (local,shard) sort IS
//      the final col order -> contiguous coalesced flush. 61KB LDS.
// Gathers (lane-owned edges, fp16 hs) and fused node kernels unchanged.

#define NEG_SLOPE 0.2f
#define PART_PER 4880   // edges per partition block
#define NBC 196         // coarse buckets per graph
#define CAPC 27072      // padded coarse-bucket capacity
#define NHALF 392       // half-buckets = NBC*2
#define CAPH 13824      // padded half-bucket capacity (col slot)
#define SHARD_DIV 50000

__device__ __forceinline__ float lrelu(float x) { return x > 0.f ? x : NEG_SLOPE * x; }
__device__ __forceinline__ float cvt(float v) { return v; }
__device__ __forceinline__ float cvt(__half v) { return __half2float(v); }

// ---------------- fused dense node kernel ----------------
template <int F, int C, bool RELU_IN, typename XT, typename HT>
__global__ void k_nodes(const XT* __restrict__ x, const float* __restrict__ Ws,
                        const float* __restrict__ a_s, const float* __restrict__ Wd_o,
                        const float* __restrict__ a_d_o, HT* __restrict__ hs,
                        float* __restrict__ alpha_s, float* __restrict__ alpha_d, int N) {
  __shared__ float sW[F * C];
  __shared__ float sa[C];
  __shared__ float sv[F];
  for (int i = threadIdx.x; i < F * C; i += blockDim.x) sW[i] = Ws[i];
  if (threadIdx.x < C) sa[threadIdx.x] = a_s[threadIdx.x];
  if (threadIdx.x < F) {
    float s = 0.f;
    for (int c = 0; c < C; ++c) s += Wd_o[threadIdx.x * C + c] * a_d_o[c];
    sv[threadIdx.x] = s;
  }
  __syncthreads();
  int n = blockIdx.x * blockDim.x + threadIdx.x;
  if (n >= N) return;
  float acc[C];
#pragma unroll
  for (int c = 0; c < C; ++c) acc[c] = 0.f;
  float ad = 0.f;
  const XT* xr = x + (size_t)n * F;
#pragma unroll 4
  for (int f = 0; f < F; ++f) {
    float xv = cvt(xr[f]);
    if (RELU_IN) xv = fmaxf(xv, 0.f);
#pragma unroll
    for (int c = 0; c < C; ++c) acc[c] += xv * sW[f * C + c];
    ad += xv * sv[f];
  }
  float al = 0.f;
#pragma unroll
  for (int c = 0; c < C; ++c) {
    if constexpr (sizeof(HT) == 2)
      hs[(size_t)n * C + c] = __float2half(acc[c]);
    else
      hs[(size_t)n * C + c] = acc[c];
    al += acc[c] * sa[c];
  }
  alpha_s[n] = al;
  alpha_d[n] = ad;
}

// ---------------- CSR stage 1: coarse partition (196 bins) ----------------
// LDS counting sort + u16 bin side array -> searchless coalesced flush.
__global__ void k_partition(const int* __restrict__ src, const int* __restrict__ dst,
                            int nE, int shift, int mask,
                            unsigned* __restrict__ part, int* __restrict__ bcnt) {
  __shared__ unsigned s_sorted[PART_PER];
  __shared__ unsigned short s_bin[PART_PER];
  __shared__ int h[256];     // counts -> excl starts
  __shared__ int ps[256];
  __shared__ int resb[256];
  __shared__ int cur[256];
  int per = (nE + gridDim.x - 1) / gridDim.x;
  int beg = blockIdx.x * per;
  int end = min(beg + per, nE);
  int cnt = end - beg;
  int t = threadIdx.x;
  h[t] = 0;
  __syncthreads();
  for (int i = beg + t; i < end; i += 256) atomicAdd(&h[dst[i] >> shift], 1);
  __syncthreads();
  int v = h[t];
  ps[t] = v;
  __syncthreads();
  for (int off = 1; off < 256; off <<= 1) {
    int u = (t >= off) ? ps[t - off] : 0;
    __syncthreads();
    ps[t] += u;
    __syncthreads();
  }
  int excl = ps[t] - v;
  resb[t] = (t < NBC && v > 0) ? atomicAdd(&bcnt[t], v) : 0;
  __syncthreads();
  h[t] = excl;
  cur[t] = excl;
  __syncthreads();
  for (int i = beg + t; i < end; i += 256) {
    int d = dst[i];
    int b = d >> shift;
    int r = atomicAdd(&cur[b], 1);
    s_sorted[r] = ((unsigned)(d & mask) << 18) | (unsigned)src[i];
    s_bin[r] = (unsigned short)b;
  }
  __syncthreads();
  for (int i = t; i < cnt; i += 256) {
    int b = s_bin[i];
    int p = resb[b] + (i - h[b]);
    if (p < CAPC) part[(size_t)b * CAPC + p] = s_sorted[i];
  }
}

// ---------------- CSR stage 2: half-bucket sort -> col + rp2 ----------------
// Block b handles coarse f=b>>1, half h=b&1. Full (local,shard) sort of the
// half in LDS; flush is CONTIGUOUS into col slot b*CAPH. rp2: [NHALF][513].
__global__ void k_sort2(const unsigned* __restrict__ part_c,
                        const int* __restrict__ bcnt_c,
                        int* __restrict__ col, int* __restrict__ rp2,
                        int hsh, int hmask, int ns, int sdiv) {
  __shared__ unsigned s_sorted[CAPH];
  __shared__ int hist[512];
  __shared__ int ps[512];
  __shared__ int cur[512];
  __shared__ int s_tot;
  int b = blockIdx.x;
  int t = threadIdx.x;
  int f = b >> 1;
  int half = b & 1;
  int cnt = min(bcnt_c[f], CAPC);
  int slot = b * CAPH;
  const unsigned* pp = part_c + (size_t)f * CAPC;
  hist[t] = 0;
  __syncthreads();
  for (int i = t; i < cnt; i += 512) {
    unsigned e = pp[i];
    int dl = (int)(e >> 18);
    if ((dl >> hsh) == half) {
      int sv = (int)(e & 0x3FFFFu);
      int bin = (ns == 4) ? ((dl & hmask) << 2) + sv / sdiv : (dl & hmask);
      atomicAdd(&hist[bin], 1);
    }
  }
  __syncthreads();
  int v = hist[t];
  ps[t] = v;
  __syncthreads();
  for (int off = 1; off < 512; off <<= 1) {
    int u = (t >= off) ? ps[t - off] : 0;
    __syncthreads();
    ps[t] += u;
    __syncthreads();
  }
  int excl = ps[t] - v;
  rp2[b * 513 + t] = slot + excl;
  if (t == 511) {
    int tot = min(ps[511], CAPH);
    rp2[b * 513 + 512] = slot + tot;
    s_tot = tot;
  }
  cur[t] = excl;
  __syncthreads();
  for (int i = t; i < cnt; i += 512) {
    unsigned e = pp[i];
    int dl = (int)(e >> 18);
    if ((dl >> hsh) == half) {
      int sv = (int)(e & 0x3FFFFu);
      int bin = (ns == 4) ? ((dl & hmask) << 2) + sv / sdiv : (dl & hmask);
      int r = atomicAdd(&cur[bin], 1);
      if (r < CAPH) s_sorted[r] = (unsigned)sv;
    }
  }
  __syncthreads();
  int tot = s_tot;
  for (int i = t; i < tot; i += 512) col[slot + i] = (int)s_sorted[i];
}

// ---------------- gathers: lane-owned edges, GROUP=16 ----------------

template <int C, typename HT>
__device__ __forceinline__ void load_row(const HT* __restrict__ hs, int s, float (&row)[C]) {
  if constexpr (sizeof(HT) == 2 && C == 16) {
    union { uint4 v[2]; __half h[16]; } buf;
    const uint4* hv = (const uint4*)(hs + (size_t)s * 16);
    buf.v[0] = hv[0];
    buf.v[1] = hv[1];
#pragma unroll
    for (int c = 0; c < 16; ++c) row[c] = __half2float(buf.h[c]);
  } else if constexpr (sizeof(HT) == 4 && C == 2) {
    float2 v = *(const float2*)((const float*)hs + (size_t)s * 2);
    row[0] = v.x;
    row[1] = v.y;
  } else {
#pragma unroll
    for (int c = 0; c < C; ++c) row[c] = cvt(hs[(size_t)s * C + c]);
  }
}

// full fused gather; half-bucket row = n>>LSH (stride 513), NSG merged bins
template <int C, int LSH, int NSG, typename HT, typename OT>
__global__ void k_gather16(const int* __restrict__ rp, const int* __restrict__ col,
                           const float* __restrict__ as, const float* __restrict__ ad,
                           const HT* __restrict__ hs, const float* __restrict__ b,
                           OT* __restrict__ out, int N) {
  int t = blockIdx.x * blockDim.x + threadIdx.x;
  int n = t >> 4;
  if (n >= N) return;
  int j = t & 15;
  int base = (n >> LSH) * 513 + (n & ((1 << LSH) - 1)) * NSG;
  int beg = rp[base];
  int end = rp[base + NSG];
  float adv = ad[n];
  float acc[C];
#pragma unroll
  for (int c = 0; c < C; ++c) acc[c] = 0.f;
  float se = 0.f;
  for (int k = beg + j; k < end; k += 16) {
    int s = col[k];
    float w = __expf(lrelu(as[s] + adv));
    se += w;
    float row[C];
    load_row<C, HT>(hs, s, row);
#pragma unroll
    for (int c = 0; c < C; ++c) acc[c] += w * row[c];
  }
#pragma unroll
  for (int m = 1; m < 16; m <<= 1) {
    se += __shfl_xor(se, m, 16);
#pragma unroll
    for (int c = 0; c < C; ++c) acc[c] += __shfl_xor(acc[c], m, 16);
  }
  if (j == 0) {
    float inv = 1.f / (se + 1e-16f);
#pragma unroll
    for (int c = 0; c < C; ++c) {
      float o = acc[c] * inv + b[c];
      if constexpr (sizeof(OT) == 2)
        out[(size_t)n * C + c] = __float2half(o);
      else
        out[(size_t)n * C + c] = o;
    }
  }
}

// sharded partial gather (ub layer 1). mode: 0=first, 1=accum, 2=finalize.
template <int C>
__global__ void k_gpart16(const int* __restrict__ rp2, const int* __restrict__ col,
                          const float* __restrict__ as, const float* __restrict__ ad,
                          const __half* __restrict__ hs, float* __restrict__ acc_g,
                          float* __restrict__ se_g, const float* __restrict__ bias,
                          __half* __restrict__ out, int N, int s, int mode) {
  int t = blockIdx.x * blockDim.x + threadIdx.x;
  int n = t >> 4;
  if (n >= N) return;
  int j = t & 15;
  int base = (n >> 7) * 513 + (n & 127) * 4 + s;
  int beg = rp2[base];
  int end = rp2[base + 1];
  float adv = ad[n];
  float acc[C];
#pragma unroll
  for (int c = 0; c < C; ++c) acc[c] = 0.f;
  float se = 0.f;
  for (int k = beg + j; k < end; k += 16) {
    int sv = col[k];
    float w = __expf(lrelu(as[sv] + adv));
    se += w;
    float row[C];
    load_row<C, __half>(hs, sv, row);
#pragma unroll
    for (int c = 0; c < C; ++c) acc[c] += w * row[c];
  }
#pragma unroll
  for (int m = 1; m < 16; m <<= 1) {
    se += __shfl_xor(se, m, 16);
#pragma unroll
    for (int c = 0; c < C; ++c) acc[c] += __shfl_xor(acc[c], m, 16);
  }
  if (j == 0) {
    float* o = acc_g + (size_t)n * C;
    if (mode == 0) {
#pragma unroll
      for (int c = 0; c < C; ++c) o[c] = acc[c];
      se_g[n] = se;
    } else if (mode == 1) {
#pragma unroll
      for (int c = 0; c < C; ++c) o[c] += acc[c];
      se_g[n] += se;
    } else {
      float st = se_g[n] + se;
      float inv = 1.f / (st + 1e-16f);
#pragma unroll
      for (int c = 0; c < C; ++c)
        out[(size_t)n * C + c] = __float2half((o[c] + acc[c]) * inv + bias[c]);
    }
  }
}

extern "C" void kernel_launch(void* const* d_in, const int* in_sizes, int n_in,
                              void* d_out, int out_size, void* d_ws, size_t ws_size,
                              hipStream_t stream) {
  const int NU = 200000, NB = 50000;
  const float* x_user  = (const float*)d_in[0];
  const float* x_badge = (const float*)d_in[1];
  const int* ub_src = (const int*)d_in[2];
  const int* ub_dst = (const int*)d_in[3];
  const int* bu_src = (const int*)d_in[4];
  const int* bu_dst = (const int*)d_in[5];
  const int nE = in_sizes[2];

  const float* W1_ub_s = (const float*)d_in[8];
  const float* W1_ub_d = (const float*)d_in[9];
  const float* a1_ub_s = (const float*)d_in[10];
  const float* a1_ub_d = (const float*)d_in[11];
  const float* b1_ub   = (const float*)d_in[12];
  const float* W2_ub_s = (const float*)d_in[13];
  const float* W2_ub_d = (const float*)d_in[14];
  const float* a2_ub_s = (const float*)d_in[15];
  const float* a2_ub_d = (const float*)d_in[16];
  const float* b2_ub   = (const float*)d_in[17];
  const float* W1_bu_s = (const float*)d_in[18];
  const float* W1_bu_d = (const float*)d_in[19];
  const float* a1_bu_s = (const float*)d_in[20];
  const float* a1_bu_d = (const float*)d_in[21];
  const float* b1_bu   = (const float*)d_in[22];
  const float* W2_bu_s = (const float*)d_in[23];
  const float* W2_bu_d = (const float*)d_in[24];
  const float* a2_bu_s = (const float*)d_in[25];
  const float* a2_bu_d = (const float*)d_in[26];
  const float* b2_bu   = (const float*)d_in[27];

  const int pblocks = (nE + PART_PER - 1) / PART_PER;

  // ---- workspace carve-up ----
  char* wsb = (char*)d_ws;
  size_t off = 0;
  auto ialloc = [&](size_t n) { int* p = (int*)(wsb + off); off += n * 4; return p; };
  int* rp2_ub = ialloc((size_t)NHALF * 513);
  int* rp2_bu = ialloc((size_t)NHALF * 513);
  int* bcnt_c = ialloc(512);  // [0:256) ub, [256:512) bu; one memset
  int* col_ub = ialloc((size_t)NHALF * CAPH);
  int* col_bu = ialloc((size_t)NHALF * CAPH);
  off = (off + 15) & ~(size_t)15;
  // UNION: part_c (dead after sort2 of graph 2) overlaid by node pool
  char* pool = wsb + off;
  unsigned* part_c = (unsigned*)pool;
  size_t poff = 0;
  auto falloc = [&](size_t n) { float* p = (float*)(pool + poff); poff += n * 4; return p; };
  auto halloc = [&](size_t n) { __half* p = (__half*)(pool + poff); poff += n * 2; return p; };
  __half* hs_u1 = halloc((size_t)NU * 16);
  __half* hs_b1 = halloc((size_t)NB * 16);
  __half* hu    = halloc((size_t)NU * 16);
  __half* hb    = halloc((size_t)NB * 16);
  float* as_u1  = falloc(NU);
  float* ad_b1  = falloc(NB);
  float* as_b1  = falloc(NB);
  float* ad_u1  = falloc(NU);
  float* hs2_ub = falloc((size_t)NU * 2);
  float* as2_ub = falloc(NU);
  float* ad2_ub = falloc(NB);
  float* hs2_bu = falloc((size_t)NB * 2);
  float* as2_bu = falloc(NB);
  float* ad2_bu = falloc(NU);
  float* acc_ub = falloc((size_t)NB * 16);
  float* se_ub  = falloc(NB);
  (void)ws_size;

  float* ou = (float*)d_out;                   // [NU,2]
  float* ob = (float*)d_out + (size_t)NU * 2;  // [NB,2]

  dim3 blk(256);
  auto g = [](int n) { return dim3((n + 255) / 256); };

  // ===== CSR build: partition -> half-bucket sort (per graph) =====
  hipMemsetAsync(bcnt_c, 0, 512 * 4, stream);
  k_partition<<<dim3(pblocks), blk, 0, stream>>>(ub_src, ub_dst, nE, 8, 255,
                                                 part_c, bcnt_c);
  k_sort2<<<dim3(NHALF), dim3(512), 0, stream>>>(part_c, bcnt_c, col_ub, rp2_ub,
                                                 7, 127, 4, SHARD_DIV);
  k_partition<<<dim3(pblocks), blk, 0, stream>>>(bu_src, bu_dst, nE, 10, 1023,
                                                 part_c, bcnt_c + 256);
  k_sort2<<<dim3(NHALF), dim3(512), 0, stream>>>(part_c, bcnt_c + 256, col_bu, rp2_bu,
                                                 9, 511, 1, 1 << 30);

  // ===== layer 1 node transforms (part_c now dead; pool writes begin) =====
  k_nodes<64, 16, false, float, __half><<<g(NU), blk, 0, stream>>>(
      x_user, W1_ub_s, a1_ub_s, W1_bu_d, a1_bu_d, hs_u1, as_u1, ad_u1, NU);
  k_nodes<64, 16, false, float, __half><<<g(NB), blk, 0, stream>>>(
      x_badge, W1_bu_s, a1_bu_s, W1_ub_d, a1_ub_d, hs_b1, as_b1, ad_b1, NB);

  // ===== layer 1 gathers =====
  for (int s = 0; s < 4; ++s)
    k_gpart16<16><<<g(NB * 16), blk, 0, stream>>>(rp2_ub, col_ub, as_u1, ad_b1, hs_u1,
                                                  acc_ub, se_ub, b1_ub, hb, NB, s,
                                                  s == 0 ? 0 : (s == 3 ? 2 : 1));
  k_gather16<16, 9, 1, __half, __half><<<g(NU * 16), blk, 0, stream>>>(
      rp2_bu, col_bu, as_b1, ad_u1, hs_b1, b1_bu, hu, NU);

  // ===== layer 2 node transforms (fp16 in, relu folded) =====
  k_nodes<16, 2, true, __half, float><<<g(NU), blk, 0, stream>>>(
      hu, W2_ub_s, a2_ub_s, W2_bu_d, a2_bu_d, hs2_ub, as2_ub, ad2_bu, NU);
  k_nodes<16, 2, true, __half, float><<<g(NB), blk, 0, stream>>>(
      hb, W2_bu_s, a2_bu_s, W2_ub_d, a2_ub_d, hs2_bu, as2_bu, ad2_ub, NB);

  // ===== layer 2 gathers (fp32 out) =====
  k_gather16<2, 7, 4, float, float><<<g(NB * 16), blk, 0, stream>>>(
      rp2_ub, col_ub, as2_ub, ad2_ub, hs2_ub, b2_ub, ob, NB);
  k_gather16<2, 9, 1, float, float><<<g(NU * 16), blk, 0, stream>>>(
      rp2_bu, col_bu, as2_bu, ad2_bu, hs2_bu, b2_bu, ou, NU);
}

// Round 11
// 617.973 us; speedup vs baseline: 1.1190x; 1.1190x over previous
//
#include <hip/hip_runtime.h>
#include <hip/hip_fp16.h>
#include <math.h>

// HeteroGNN: 2-layer bipartite single-head GAT (users<->badges).
// R11: pipeline restructure (R10 post-mortem: partition is OCCUPANCY-bound,
// 1025 blocks < 1536 resident capacity; 5-launch L1 gather serializes):
//   - partition reverted to R9 internals (24KB LDS, binary-search flush),
//     BOTH graphs fused in one 2050-block dispatch (fills the machine)
//   - sort2 both graphs in one 784-block dispatch
//   - megaL1: 4 ub shards with PRIVATE acc slices (no RMW serialization),
//     XCD-pinned via blockIdx&7 (shard s -> XCDs 2s,2s+1) + bu gather in
//     the same grid; bu epilogue computes layer-2 user transforms inline
//     (hu never materialized)
//   - finalize(badges) computes layer-2 badge transforms inline (no hb)
//   - fused L2 output gather. 7 dispatches total (was 14).

#define NEG_SLOPE 0.2f
#define PART_PER 4880
#define NBC 196
#define CAPC 27072
#define NHALF 392
#define CAPH 13824
#define SHARD_DIV 50000

__device__ __forceinline__ float lrelu(float x) { return x > 0.f ? x : NEG_SLOPE * x; }

// ---------------- layer-1 node transforms, both node sets ----------------
__global__ void k_nodes1_both(
    const float* __restrict__ xu, const float* __restrict__ xb,
    const float* __restrict__ Wub_s, const float* __restrict__ aub_s,
    const float* __restrict__ Wbu_d, const float* __restrict__ abu_d,
    const float* __restrict__ Wbu_s, const float* __restrict__ abu_s,
    const float* __restrict__ Wub_d, const float* __restrict__ aub_d,
    __half* __restrict__ hs_u, float* __restrict__ as_u, float* __restrict__ ad_u,
    __half* __restrict__ hs_b, float* __restrict__ as_b, float* __restrict__ ad_b,
    int NU, int NB, int gNU) {
  __shared__ float sW[64 * 16];
  __shared__ float sa[16];
  __shared__ float sv[64];
  int blk = blockIdx.x;
  bool us = blk < gNU;
  const float* x  = us ? xu : xb;
  const float* Ws = us ? Wub_s : Wbu_s;
  const float* As = us ? aub_s : abu_s;
  const float* Wd = us ? Wbu_d : Wub_d;  // other relation's dst projection
  const float* Ad = us ? abu_d : aub_d;
  __half* hs = us ? hs_u : hs_b;
  float* als = us ? as_u : as_b;
  float* ald = us ? ad_u : ad_b;
  int N = us ? NU : NB;
  int t = threadIdx.x;
  for (int i = t; i < 64 * 16; i += 256) sW[i] = Ws[i];
  if (t < 16) sa[t] = As[t];
  if (t < 64) {
    float s = 0.f;
    for (int c = 0; c < 16; ++c) s += Wd[t * 16 + c] * Ad[c];
    sv[t] = s;
  }
  __syncthreads();
  int n = (us ? blk : blk - gNU) * 256 + t;
  if (n >= N) return;
  float acc[16];
#pragma unroll
  for (int c = 0; c < 16; ++c) acc[c] = 0.f;
  float ad = 0.f;
  const float* xr = x + (size_t)n * 64;
#pragma unroll 4
  for (int f = 0; f < 64; ++f) {
    float xv = xr[f];
#pragma unroll
    for (int c = 0; c < 16; ++c) acc[c] += xv * sW[f * 16 + c];
    ad += xv * sv[f];
  }
  float al = 0.f;
#pragma unroll
  for (int c = 0; c < 16; ++c) {
    hs[(size_t)n * 16 + c] = __float2half(acc[c]);
    al += acc[c] * sa[c];
  }
  als[n] = al;
  ald[n] = ad;
}

// ---------------- CSR stage 1: both graphs, R9 internals ----------------
__global__ void k_partition2(const int* __restrict__ src0, const int* __restrict__ dst0,
                             const int* __restrict__ src1, const int* __restrict__ dst1,
                             int nE, int pblocks,
                             unsigned* __restrict__ part0, unsigned* __restrict__ part1,
                             int* __restrict__ bcnt) {
  __shared__ unsigned s_sorted[PART_PER];
  __shared__ int h[257];
  __shared__ int ps[256];
  __shared__ int resb[256];
  __shared__ int cur[256];
  int gb = blockIdx.x;
  const int* src; const int* dst; unsigned* part; int* bc; int shift; int mask;
  if (gb < pblocks) { src = src0; dst = dst0; part = part0; bc = bcnt; shift = 8; mask = 255; }
  else { gb -= pblocks; src = src1; dst = dst1; part = part1; bc = bcnt + 256; shift = 10; mask = 1023; }
  int per = (nE + pblocks - 1) / pblocks;
  int beg = gb * per;
  int end = min(beg + per, nE);
  int cnt = end - beg;
  int t = threadIdx.x;
  h[t] = 0;
  __syncthreads();
  for (int i = beg + t; i < end; i += 256) atomicAdd(&h[dst[i] >> shift], 1);
  __syncthreads();
  int v = h[t];
  ps[t] = v;
  __syncthreads();
  for (int off = 1; off < 256; off <<= 1) {
    int u = (t >= off) ? ps[t - off] : 0;
    __syncthreads();
    ps[t] += u;
    __syncthreads();
  }
  int excl = ps[t] - v;
  resb[t] = (t < NBC && v > 0) ? atomicAdd(&bc[t], v) : 0;
  __syncthreads();
  h[t] = excl;
  cur[t] = excl;
  if (t == 255) h[256] = excl + v;
  __syncthreads();
  for (int i = beg + t; i < end; i += 256) {
    int d = dst[i];
    int b = d >> shift;
    int r = atomicAdd(&cur[b], 1);
    s_sorted[r] = ((unsigned)(d & mask) << 18) | (unsigned)src[i];
  }
  __syncthreads();
  for (int i = t; i < cnt; i += 256) {
    int lo = 0, hi = 256;
    while (hi - lo > 1) {
      int mid = (lo + hi) >> 1;
      if (h[mid] <= i) lo = mid; else hi = mid;
    }
    int p = resb[lo] + (i - h[lo]);
    if (p < CAPC) part[(size_t)lo * CAPC + p] = s_sorted[i];
  }
}

// ---------------- CSR stage 2: half-bucket sort, both graphs ----------------
__global__ void k_sort2_both(const unsigned* __restrict__ part0,
                             const unsigned* __restrict__ part1,
                             const int* __restrict__ bcnt,
                             int* __restrict__ col0, int* __restrict__ col1,
                             int* __restrict__ rp0, int* __restrict__ rp1) {
  __shared__ unsigned s_sorted[CAPH];
  __shared__ int hist[512];
  __shared__ int ps[512];
  __shared__ int cur[512];
  __shared__ int s_tot;
  int bb = blockIdx.x;
  const unsigned* part; const int* bc; int* col; int* rp;
  int hsh, hmask, ns, sdiv;
  if (bb < NHALF) { part = part0; bc = bcnt; col = col0; rp = rp0;
                    hsh = 7; hmask = 127; ns = 4; sdiv = SHARD_DIV; }
  else { bb -= NHALF; part = part1; bc = bcnt + 256; col = col1; rp = rp1;
         hsh = 9; hmask = 511; ns = 1; sdiv = 1 << 30; }
  int t = threadIdx.x;
  int f = bb >> 1;
  int half = bb & 1;
  int cnt = min(bc[f], CAPC);
  int slot = bb * CAPH;
  const unsigned* pp = part + (size_t)f * CAPC;
  hist[t] = 0;
  __syncthreads();
  for (int i = t; i < cnt; i += 512) {
    unsigned e = pp[i];
    int dl = (int)(e >> 18);
    if ((dl >> hsh) == half) {
      int sv = (int)(e & 0x3FFFFu);
      int bin = (ns == 4) ? ((dl & hmask) << 2) + sv / sdiv : (dl & hmask);
      atomicAdd(&hist[bin], 1);
    }
  }
  __syncthreads();
  int v = hist[t];
  ps[t] = v;
  __syncthreads();
  for (int off = 1; off < 512; off <<= 1) {
    int u = (t >= off) ? ps[t - off] : 0;
    __syncthreads();
    ps[t] += u;
    __syncthreads();
  }
  int excl = ps[t] - v;
  rp[bb * 513 + t] = slot + excl;
  if (t == 511) {
    int tot = min(ps[511], CAPH);
    rp[bb * 513 + 512] = slot + tot;
    s_tot = tot;
  }
  cur[t] = excl;
  __syncthreads();
  for (int i = t; i < cnt; i += 512) {
    unsigned e = pp[i];
    int dl = (int)(e >> 18);
    if ((dl >> hsh) == half) {
      int sv = (int)(e & 0x3FFFFu);
      int bin = (ns == 4) ? ((dl & hmask) << 2) + sv / sdiv : (dl & hmask);
      int r = atomicAdd(&cur[bin], 1);
      if (r < CAPH) s_sorted[r] = (unsigned)sv;
    }
  }
  __syncthreads();
  int tot = s_tot;
  for (int i = t; i < tot; i += 512) col[slot + i] = (int)s_sorted[i];
}

// ---------------- mega layer-1 gather ----------------
__device__ __forceinline__ void load_row16h(const __half* __restrict__ hs, int s,
                                            float (&row)[16]) {
  union { uint4 v[2]; __half h[16]; } buf;
  const uint4* hv = (const uint4*)(hs + (size_t)s * 16);
  buf.v[0] = hv[0];
  buf.v[1] = hv[1];
#pragma unroll
  for (int c = 0; c < 16; ++c) row[c] = __half2float(buf.h[c]);
}

__global__ void k_megaL1(
    const int* __restrict__ rp_ub, const int* __restrict__ col_ub,
    const float* __restrict__ as_u, const float* __restrict__ ad_b,
    const __half* __restrict__ hs_u,
    float* __restrict__ acc_sl, float* __restrict__ se_sl,
    const int* __restrict__ rp_bu, const int* __restrict__ col_bu,
    const float* __restrict__ as_b, const float* __restrict__ ad_u,
    const __half* __restrict__ hs_b,
    const float* __restrict__ b1bu,
    const float* __restrict__ W2ub_s, const float* __restrict__ a2ub_s,
    const float* __restrict__ W2bu_d, const float* __restrict__ a2bu_d,
    float* __restrict__ hs2_ub, float* __restrict__ as2_ub, float* __restrict__ ad2_bu,
    int NB, int NU, int ubBlocks) {
  __shared__ float sW2[32], sa2[2], sv2[16], sb1[16];
  int t = threadIdx.x;
  if (t < 32) sW2[t] = W2ub_s[t];
  if (t < 2) sa2[t] = a2ub_s[t];
  if (t < 16) {
    float s = 0.f;
    for (int cc = 0; cc < 2; ++cc) s += W2bu_d[t * 2 + cc] * a2bu_d[cc];
    sv2[t] = s;
    sb1[t] = b1bu[t];
  }
  __syncthreads();
  int b = blockIdx.x;
  int j = t & 15;
  if (b < ubBlocks) {
    // ub sharded gather, XCD-pinned: shard s on XCDs {2s, 2s+1}
    int xcd = b & 7;
    int s = xcd >> 1;
    int sub = ((b >> 3) << 1) | (xcd & 1);
    int n = sub * 16 + (t >> 4);
    if (n >= NB) return;
    int base = (n >> 7) * 513 + (n & 127) * 4 + s;
    int beg = rp_ub[base], end = rp_ub[base + 1];
    float adv = ad_b[n];
    float acc[16];
#pragma unroll
    for (int c = 0; c < 16; ++c) acc[c] = 0.f;
    float se = 0.f;
    for (int k = beg + j; k < end; k += 16) {
      int sv = col_ub[k];
      float w = __expf(lrelu(as_u[sv] + adv));
      se += w;
      float row[16];
      load_row16h(hs_u, sv, row);
#pragma unroll
      for (int c = 0; c < 16; ++c) acc[c] += w * row[c];
    }
#pragma unroll
    for (int m = 1; m < 16; m <<= 1) {
      se += __shfl_xor(se, m, 16);
#pragma unroll
      for (int c = 0; c < 16; ++c) acc[c] += __shfl_xor(acc[c], m, 16);
    }
    if (j == 0) {
      float* o = acc_sl + ((size_t)s * NB + n) * 16;
#pragma unroll
      for (int c = 0; c < 16; ++c) o[c] = acc[c];
      se_sl[s * NB + n] = se;
    }
  } else {
    // bu gather + inline layer-2 user transform (hu never materialized)
    int n = (b - ubBlocks) * 16 + (t >> 4);
    if (n >= NU) return;
    int base = (n >> 9) * 513 + (n & 511);
    int beg = rp_bu[base], end = rp_bu[base + 1];
    float adv = ad_u[n];
    float acc[16];
#pragma unroll
    for (int c = 0; c < 16; ++c) acc[c] = 0.f;
    float se = 0.f;
    for (int k = beg + j; k < end; k += 16) {
      int sv = col_bu[k];
      float w = __expf(lrelu(as_b[sv] + adv));
      se += w;
      float row[16];
      load_row16h(hs_b, sv, row);
#pragma unroll
      for (int c = 0; c < 16; ++c) acc[c] += w * row[c];
    }
#pragma unroll
    for (int m = 1; m < 16; m <<= 1) {
      se += __shfl_xor(se, m, 16);
#pragma unroll
      for (int c = 0; c < 16; ++c) acc[c] += __shfl_xor(acc[c], m, 16);
    }
    if (j == 0) {
      float inv = 1.f / (se + 1e-16f);
      float h0 = 0.f, h1 = 0.f, advn = 0.f;
#pragma unroll
      for (int c = 0; c < 16; ++c) {
        float xv = fmaxf(acc[c] * inv + sb1[c], 0.f);
        h0 += xv * sW2[c * 2];
        h1 += xv * sW2[c * 2 + 1];
        advn += xv * sv2[c];
      }
      hs2_ub[(size_t)n * 2] = h0;
      hs2_ub[(size_t)n * 2 + 1] = h1;
      as2_ub[n] = h0 * sa2[0] + h1 * sa2[1];
      ad2_bu[n] = advn;
    }
  }
}

// ---------------- finalize badges + inline layer-2 badge transform ----------------
__global__ void k_finL1b(
    const float* __restrict__ acc_sl, const float* __restrict__ se_sl,
    const float* __restrict__ b1ub,
    const float* __restrict__ W2bu_s, const float* __restrict__ a2bu_s,
    const float* __restrict__ W2ub_d, const float* __restrict__ a2ub_d,
    float* __restrict__ hs2_bu, float* __restrict__ as2_bu, float* __restrict__ ad2_ub,
    int NB) {
  __shared__ float sW2[32], sa2[2], sv2[16], sb1[16];
  int t = threadIdx.x;
  if (t < 32) sW2[t] = W2bu_s[t];
  if (t < 2) sa2[t] = a2bu_s[t];
  if (t < 16) {
    float s = 0.f;
    for (int cc = 0; cc < 2; ++cc) s += W2ub_d[t * 2 + cc] * a2ub_d[cc];
    sv2[t] = s;
    sb1[t] = b1ub[t];
  }
  __syncthreads();
  int n = blockIdx.x * 256 + t;
  if (n >= NB) return;
  float a[16];
#pragma unroll
  for (int c = 0; c < 16; ++c) a[c] = 0.f;
  float se = 0.f;
  for (int s = 0; s < 4; ++s) {
    const float4* p = (const float4*)(acc_sl + ((size_t)s * NB + n) * 16);
    float4 v0 = p[0], v1 = p[1], v2 = p[2], v3 = p[3];
    a[0] += v0.x; a[1] += v0.y; a[2] += v0.z; a[3] += v0.w;
    a[4] += v1.x; a[5] += v1.y; a[6] += v1.z; a[7] += v1.w;
    a[8] += v2.x; a[9] += v2.y; a[10] += v2.z; a[11] += v2.w;
    a[12] += v3.x; a[13] += v3.y; a[14] += v3.z; a[15] += v3.w;
    se += se_sl[s * NB + n];
  }
  float inv = 1.f / (se + 1e-16f);
  float h0 = 0.f, h1 = 0.f, advn = 0.f;
#pragma unroll
  for (int c = 0; c < 16; ++c) {
    float xv = fmaxf(a[c] * inv + sb1[c], 0.f);
    h0 += xv * sW2[c * 2];
    h1 += xv * sW2[c * 2 + 1];
    advn += xv * sv2[c];
  }
  hs2_bu[(size_t)n * 2] = h0;
  hs2_bu[(size_t)n * 2 + 1] = h1;
  as2_bu[n] = h0 * sa2[0] + h1 * sa2[1];
  ad2_ub[n] = advn;
}

// ---------------- fused layer-2 output gathers ----------------
__global__ void k_gatherL2(
    const int* __restrict__ rp0, const int* __restrict__ col0,
    const float* __restrict__ as0, const float* __restrict__ ad0,
    const float* __restrict__ hs0, const float* __restrict__ b0,
    float* __restrict__ out0, int N0,  // badges (lsh 7, nsg 4)
    const int* __restrict__ rp1, const int* __restrict__ col1,
    const float* __restrict__ as1, const float* __restrict__ ad1,
    const float* __restrict__ hs1, const float* __restrict__ b1,
    float* __restrict__ out1, int N1,  // users (lsh 9, nsg 1)
    int g0) {
  int blk = blockIdx.x;
  const int *rp, *col; const float *as, *ad, *hs, *bb; float* out;
  int N, lsh, nsg;
  if (blk < g0) { rp = rp0; col = col0; as = as0; ad = ad0; hs = hs0; bb = b0;
                  out = out0; N = N0; lsh = 7; nsg = 4; }
  else { blk -= g0; rp = rp1; col = col1; as = as1; ad = ad1; hs = hs1; bb = b1;
         out = out1; N = N1; lsh = 9; nsg = 1; }
  int n = blk * 16 + (threadIdx.x >> 4);
  int j = threadIdx.x & 15;
  if (n >= N) return;
  int base = (n >> lsh) * 513 + (n & ((1 << lsh) - 1)) * nsg;
  int beg = rp[base], end = rp[base + nsg];
  float adv = ad[n];
  float a0 = 0.f, a1 = 0.f, se = 0.f;
  for (int k = beg + j; k < end; k += 16) {
    int s = col[k];
    float w = __expf(lrelu(as[s] + adv));
    se += w;
    float2 v = *(const float2*)(hs + (size_t)s * 2);
    a0 += w * v.x;
    a1 += w * v.y;
  }
#pragma unroll
  for (int m = 1; m < 16; m <<= 1) {
    se += __shfl_xor(se, m, 16);
    a0 += __shfl_xor(a0, m, 16);
    a1 += __shfl_xor(a1, m, 16);
  }
  if (j == 0) {
    float inv = 1.f / (se + 1e-16f);
    out[(size_t)n * 2] = a0 * inv + bb[0];
    out[(size_t)n * 2 + 1] = a1 * inv + bb[1];
  }
}

extern "C" void kernel_launch(void* const* d_in, const int* in_sizes, int n_in,
                              void* d_out, int out_size, void* d_ws, size_t ws_size,
                              hipStream_t stream) {
  const int NU = 200000, NB = 50000;
  const float* x_user  = (const float*)d_in[0];
  const float* x_badge = (const float*)d_in[1];
  const int* ub_src = (const int*)d_in[2];
  const int* ub_dst = (const int*)d_in[3];
  const int* bu_src = (const int*)d_in[4];
  const int* bu_dst = (const int*)d_in[5];
  const int nE = in_sizes[2];

  const float* W1_ub_s = (const float*)d_in[8];
  const float* W1_ub_d = (const float*)d_in[9];
  const float* a1_ub_s = (const float*)d_in[10];
  const float* a1_ub_d = (const float*)d_in[11];
  const float* b1_ub   = (const float*)d_in[12];
  const float* W2_ub_s = (const float*)d_in[13];
  const float* W2_ub_d = (const float*)d_in[14];
  const float* a2_ub_s = (const float*)d_in[15];
  const float* a2_ub_d = (const float*)d_in[16];
  const float* b2_ub   = (const float*)d_in[17];
  const float* W1_bu_s = (const float*)d_in[18];
  const float* W1_bu_d = (const float*)d_in[19];
  const float* a1_bu_s = (const float*)d_in[20];
  const float* a1_bu_d = (const float*)d_in[21];
  const float* b1_bu   = (const float*)d_in[22];
  const float* W2_bu_s = (const float*)d_in[23];
  const float* W2_bu_d = (const float*)d_in[24];
  const float* a2_bu_s = (const float*)d_in[25];
  const float* a2_bu_d = (const float*)d_in[26];
  const float* b2_bu   = (const float*)d_in[27];

  const int pblocks = (nE + PART_PER - 1) / PART_PER;

  // ---- workspace carve-up ----
  char* wsb = (char*)d_ws;
  size_t off = 0;
  auto ialloc = [&](size_t n) { int* p = (int*)(wsb + off); off += n * 4; return p; };
  int* rp2_ub = ialloc((size_t)NHALF * 513);
  int* rp2_bu = ialloc((size_t)NHALF * 513);
  int* bcnt   = ialloc(512);  // [0:256) ub, [256:512) bu; one memset
  int* col_ub = ialloc((size_t)NHALF * CAPH);
  int* col_bu = ialloc((size_t)NHALF * CAPH);
  off = (off + 15) & ~(size_t)15;
  // UNION: part0+part1 (dead after sort2) overlaid by node pool
  char* pool = wsb + off;
  unsigned* part0 = (unsigned*)pool;
  unsigned* part1 = (unsigned*)(pool + (size_t)NBC * CAPC * 4);
  size_t poff = 0;
  auto falloc = [&](size_t n) { float* p = (float*)(pool + poff); poff += n * 4; return p; };
  auto halloc = [&](size_t n) { __half* p = (__half*)(pool + poff); poff += n * 2; return p; };
  __half* hs_u1 = halloc((size_t)NU * 16);
  __half* hs_b1 = halloc((size_t)NB * 16);
  float* as_u1  = falloc(NU);
  float* ad_b1  = falloc(NB);
  float* as_b1  = falloc(NB);
  float* ad_u1  = falloc(NU);
  float* hs2_ub = falloc((size_t)NU * 2);
  float* as2_ub = falloc(NU);
  float* ad2_ub = falloc(NB);
  float* hs2_bu = falloc((size_t)NB * 2);
  float* as2_bu = falloc(NB);
  float* ad2_bu = falloc(NU);
  float* acc_sl = falloc((size_t)4 * NB * 16);
  float* se_sl  = falloc((size_t)4 * NB);
  (void)ws_size;

  float* ou = (float*)d_out;                   // [NU,2]
  float* ob = (float*)d_out + (size_t)NU * 2;  // [NB,2]

  const int gNU = (NU + 255) / 256;        // 782
  const int gNB = (NB + 255) / 256;        // 196
  const int ubBlocks = ((NB / 16 + 1) / 2 + 1) * 8;  // 1564*8: covers sub<3128
  const int buBlocks = (NU * 16 + 255) / 256;        // 12500
  const int g0 = (NB * 16 + 255) / 256;    // 3125
  const int g1 = buBlocks;

  // ===== 7 dispatches =====
  hipMemsetAsync(bcnt, 0, 512 * 4, stream);
  k_partition2<<<dim3(2 * pblocks), dim3(256), 0, stream>>>(
      ub_src, ub_dst, bu_src, bu_dst, nE, pblocks, part0, part1, bcnt);
  k_sort2_both<<<dim3(2 * NHALF), dim3(512), 0, stream>>>(
      part0, part1, bcnt, col_ub, col_bu, rp2_ub, rp2_bu);
  k_nodes1_both<<<dim3(gNU + gNB), dim3(256), 0, stream>>>(
      x_user, x_badge, W1_ub_s, a1_ub_s, W1_bu_d, a1_bu_d,
      W1_bu_s, a1_bu_s, W1_ub_d, a1_ub_d,
      hs_u1, as_u1, ad_u1, hs_b1, as_b1, ad_b1, NU, NB, gNU);
  k_megaL1<<<dim3(ubBlocks + buBlocks), dim3(256), 0, stream>>>(
      rp2_ub, col_ub, as_u1, ad_b1, hs_u1, acc_sl, se_sl,
      rp2_bu, col_bu, as_b1, ad_u1, hs_b1,
      b1_bu, W2_ub_s, a2_ub_s, W2_bu_d, a2_bu_d,
      hs2_ub, as2_ub, ad2_bu, NB, NU, ubBlocks);
  k_finL1b<<<dim3(gNB), dim3(256), 0, stream>>>(
      acc_sl, se_sl, b1_ub, W2_bu_s, a2_bu_s, W2_ub_d, a2_ub_d,
      hs2_bu, as2_bu, ad2_ub, NB);
  k_gatherL2<<<dim3(g0 + g1), dim3(256), 0, stream>>>(
      rp2_ub, col_ub, as2_ub, ad2_ub, hs2_ub, b2_ub, ob, NB,
      rp2_bu, col_bu, as2_bu, ad2_bu, hs2_bu, b2_bu, ou, NU, g0);
}

// Round 12
// 552.539 us; speedup vs baseline: 1.2515x; 1.1184x over previous
//
#include <hip/hip_runtime.h>
#include <hip/hip_fp16.h>
#include <math.h>

// HeteroGNN: 2-layer bipartite single-head GAT (users<->badges).
// R12 (from R11 @618us, partition2 125us latency-bound at 46% occ):
//   - k_stageA = partition2 + nodes1_both fused (independent work fills
//     partition's latency bubbles); union LDS 23.6KB keeps 6 blocks/CU.
//   - partition flush: 4-way unrolled binary search (4 independent LDS
//     dependency chains/thread -> chain latency /4, zero LDS growth).
//   - layer-2 node data packed as float4 pk[n]={alpha_s,h0,h1,alpha_d}:
//     gatherL2 does ONE 16B random load per edge (was 4B+8B).
//   - runtime ws_size check: if too small for the no-overlay layout, fall
//     back to R11 ordering (nodes after sort2, overlaying part).

#define NEG_SLOPE 0.2f
#define PART_PER 4880
#define NBC 196
#define CAPC 27072
#define NHALF 392
#define CAPH 13824
#define SHARD_DIV 50000

__device__ __forceinline__ float lrelu(float x) { return x > 0.f ? x : NEG_SLOPE * x; }

// ---------------- stage A: coarse partition (both graphs) + L1 node transforms ----------------
__global__ void k_stageA(
    const int* __restrict__ src0, const int* __restrict__ dst0,
    const int* __restrict__ src1, const int* __restrict__ dst1,
    int nE, int pblocks, unsigned* __restrict__ part0, unsigned* __restrict__ part1,
    int* __restrict__ bcnt,
    const float* __restrict__ xu, const float* __restrict__ xb,
    const float* __restrict__ Wub_s, const float* __restrict__ aub_s,
    const float* __restrict__ Wbu_d, const float* __restrict__ abu_d,
    const float* __restrict__ Wbu_s, const float* __restrict__ abu_s,
    const float* __restrict__ Wub_d, const float* __restrict__ aub_d,
    __half* __restrict__ hs_u, float* __restrict__ as_u, float* __restrict__ ad_u,
    __half* __restrict__ hs_b, float* __restrict__ as_b, float* __restrict__ ad_b,
    int NU, int NB, int gNU, int partBlocks) {
  union Sm {
    struct { unsigned s_sorted[PART_PER]; int h[257]; int ps[256]; int resb[256]; int cur[256]; } p;
    struct { float sW[64 * 16]; float sa[16]; float sv[64]; } n;
  };
  __shared__ Sm sm;
  int t = threadIdx.x;
  int b = blockIdx.x;
  if (b < partBlocks) {
    // ===== partition branch =====
    int gb = b;
    const int* src; const int* dst; unsigned* part; int* bc; int shift; int mask;
    if (gb < pblocks) { src = src0; dst = dst0; part = part0; bc = bcnt; shift = 8; mask = 255; }
    else { gb -= pblocks; src = src1; dst = dst1; part = part1; bc = bcnt + 256; shift = 10; mask = 1023; }
    int per = (nE + pblocks - 1) / pblocks;
    int beg = gb * per;
    int end = min(beg + per, nE);
    int cnt = end - beg;
    sm.p.h[t] = 0;
    __syncthreads();
    for (int i = beg + t; i < end; i += 256) atomicAdd(&sm.p.h[dst[i] >> shift], 1);
    __syncthreads();
    int v = sm.p.h[t];
    sm.p.ps[t] = v;
    __syncthreads();
    for (int off = 1; off < 256; off <<= 1) {
      int u = (t >= off) ? sm.p.ps[t - off] : 0;
      __syncthreads();
      sm.p.ps[t] += u;
      __syncthreads();
    }
    int excl = sm.p.ps[t] - v;
    sm.p.resb[t] = (t < NBC && v > 0) ? atomicAdd(&bc[t], v) : 0;
    __syncthreads();
    sm.p.h[t] = excl;
    sm.p.cur[t] = excl;
    if (t == 255) sm.p.h[256] = excl + v;
    __syncthreads();
    for (int i = beg + t; i < end; i += 256) {
      int d = dst[i];
      int bb = d >> shift;
      int r = atomicAdd(&sm.p.cur[bb], 1);
      sm.p.s_sorted[r] = ((unsigned)(d & mask) << 18) | (unsigned)src[i];
    }
    __syncthreads();
    // flush: 4 concurrent binary-search chains per thread (ILP)
    for (int i = t; i < cnt; i += 1024) {
      int i1 = i + 256, i2 = i + 512, i3 = i + 768;
      int lo0 = 0, lo1 = 0, lo2 = 0, lo3 = 0;
      int hi0 = 256, hi1 = 256, hi2 = 256, hi3 = 256;
#pragma unroll
      for (int s = 0; s < 8; ++s) {
        int m0 = (lo0 + hi0) >> 1; if (sm.p.h[m0] <= i)  lo0 = m0; else hi0 = m0;
        int m1 = (lo1 + hi1) >> 1; if (sm.p.h[m1] <= i1) lo1 = m1; else hi1 = m1;
        int m2 = (lo2 + hi2) >> 1; if (sm.p.h[m2] <= i2) lo2 = m2; else hi2 = m2;
        int m3 = (lo3 + hi3) >> 1; if (sm.p.h[m3] <= i3) lo3 = m3; else hi3 = m3;
      }
      { int p = sm.p.resb[lo0] + (i - sm.p.h[lo0]);
        if (p < CAPC) part[(size_t)lo0 * CAPC + p] = sm.p.s_sorted[i]; }
      if (i1 < cnt) { int p = sm.p.resb[lo1] + (i1 - sm.p.h[lo1]);
        if (p < CAPC) part[(size_t)lo1 * CAPC + p] = sm.p.s_sorted[i1]; }
      if (i2 < cnt) { int p = sm.p.resb[lo2] + (i2 - sm.p.h[lo2]);
        if (p < CAPC) part[(size_t)lo2 * CAPC + p] = sm.p.s_sorted[i2]; }
      if (i3 < cnt) { int p = sm.p.resb[lo3] + (i3 - sm.p.h[lo3]);
        if (p < CAPC) part[(size_t)lo3 * CAPC + p] = sm.p.s_sorted[i3]; }
    }
    return;
  }
  // ===== nodes branch =====
  int blk = b - partBlocks;
  bool us = blk < gNU;
  const float* x  = us ? xu : xb;
  const float* Ws = us ? Wub_s : Wbu_s;
  const float* As = us ? aub_s : abu_s;
  const float* Wd = us ? Wbu_d : Wub_d;
  const float* Ad = us ? abu_d : aub_d;
  __half* hs = us ? hs_u : hs_b;
  float* als = us ? as_u : as_b;
  float* ald = us ? ad_u : ad_b;
  int N = us ? NU : NB;
  for (int i = t; i < 64 * 16; i += 256) sm.n.sW[i] = Ws[i];
  if (t < 16) sm.n.sa[t] = As[t];
  if (t < 64) {
    float s = 0.f;
    for (int c = 0; c < 16; ++c) s += Wd[t * 16 + c] * Ad[c];
    sm.n.sv[t] = s;
  }
  __syncthreads();
  int n = (us ? blk : blk - gNU) * 256 + t;
  if (n >= N) return;
  float acc[16];
#pragma unroll
  for (int c = 0; c < 16; ++c) acc[c] = 0.f;
  float ad = 0.f;
  const float* xr = x + (size_t)n * 64;
#pragma unroll 4
  for (int f = 0; f < 64; ++f) {
    float xv = xr[f];
#pragma unroll
    for (int c = 0; c < 16; ++c) acc[c] += xv * sm.n.sW[f * 16 + c];
    ad += xv * sm.n.sv[f];
  }
  float al = 0.f;
#pragma unroll
  for (int c = 0; c < 16; ++c) {
    hs[(size_t)n * 16 + c] = __float2half(acc[c]);
    al += acc[c] * sm.n.sa[c];
  }
  als[n] = al;
  ald[n] = ad;
}

// ---------------- CSR stage 2: half-bucket sort, both graphs ----------------
__global__ void k_sort2_both(const unsigned* __restrict__ part0,
                             const unsigned* __restrict__ part1,
                             const int* __restrict__ bcnt,
                             int* __restrict__ col0, int* __restrict__ col1,
                             int* __restrict__ rp0, int* __restrict__ rp1) {
  __shared__ unsigned s_sorted[CAPH];
  __shared__ int hist[512];
  __shared__ int ps[512];
  __shared__ int cur[512];
  __shared__ int s_tot;
  int bb = blockIdx.x;
  const unsigned* part; const int* bc; int* col; int* rp;
  int hsh, hmask, ns, sdiv;
  if (bb < NHALF) { part = part0; bc = bcnt; col = col0; rp = rp0;
                    hsh = 7; hmask = 127; ns = 4; sdiv = SHARD_DIV; }
  else { bb -= NHALF; part = part1; bc = bcnt + 256; col = col1; rp = rp1;
         hsh = 9; hmask = 511; ns = 1; sdiv = 1 << 30; }
  int t = threadIdx.x;
  int f = bb >> 1;
  int half = bb & 1;
  int cnt = min(bc[f], CAPC);
  int slot = bb * CAPH;
  const unsigned* pp = part + (size_t)f * CAPC;
  hist[t] = 0;
  __syncthreads();
  for (int i = t; i < cnt; i += 512) {
    unsigned e = pp[i];
    int dl = (int)(e >> 18);
    if ((dl >> hsh) == half) {
      int sv = (int)(e & 0x3FFFFu);
      int bin = (ns == 4) ? ((dl & hmask) << 2) + sv / sdiv : (dl & hmask);
      atomicAdd(&hist[bin], 1);
    }
  }
  __syncthreads();
  int v = hist[t];
  ps[t] = v;
  __syncthreads();
  for (int off = 1; off < 512; off <<= 1) {
    int u = (t >= off) ? ps[t - off] : 0;
    __syncthreads();
    ps[t] += u;
    __syncthreads();
  }
  int excl = ps[t] - v;
  rp[bb * 513 + t] = slot + excl;
  if (t == 511) {
    int tot = min(ps[511], CAPH);
    rp[bb * 513 + 512] = slot + tot;
    s_tot = tot;
  }
  cur[t] = excl;
  __syncthreads();
  for (int i = t; i < cnt; i += 512) {
    unsigned e = pp[i];
    int dl = (int)(e >> 18);
    if ((dl >> hsh) == half) {
      int sv = (int)(e & 0x3FFFFu);
      int bin = (ns == 4) ? ((dl & hmask) << 2) + sv / sdiv : (dl & hmask);
      int r = atomicAdd(&cur[bin], 1);
      if (r < CAPH) s_sorted[r] = (unsigned)sv;
    }
  }
  __syncthreads();
  int tot = s_tot;
  for (int i = t; i < tot; i += 512) col[slot + i] = (int)s_sorted[i];
}

// ---------------- mega layer-1 gather ----------------
__device__ __forceinline__ void load_row16h(const __half* __restrict__ hs, int s,
                                            float (&row)[16]) {
  union { uint4 v[2]; __half h[16]; } buf;
  const uint4* hv = (const uint4*)(hs + (size_t)s * 16);
  buf.v[0] = hv[0];
  buf.v[1] = hv[1];
#pragma unroll
  for (int c = 0; c < 16; ++c) row[c] = __half2float(buf.h[c]);
}

__global__ void k_megaL1(
    const int* __restrict__ rp_ub, const int* __restrict__ col_ub,
    const float* __restrict__ as_u, const float* __restrict__ ad_b,
    const __half* __restrict__ hs_u,
    float* __restrict__ acc_sl, float* __restrict__ se_sl,
    const int* __restrict__ rp_bu, const int* __restrict__ col_bu,
    const float* __restrict__ as_b, const float* __restrict__ ad_u,
    const __half* __restrict__ hs_b,
    const float* __restrict__ b1bu,
    const float* __restrict__ W2ub_s, const float* __restrict__ a2ub_s,
    const float* __restrict__ W2bu_d, const float* __restrict__ a2bu_d,
    float4* __restrict__ pk_u, int NB, int NU, int ubBlocks) {
  __shared__ float sW2[32], sa2[2], sv2[16], sb1[16];
  int t = threadIdx.x;
  if (t < 32) sW2[t] = W2ub_s[t];
  if (t < 2) sa2[t] = a2ub_s[t];
  if (t < 16) {
    float s = 0.f;
    for (int cc = 0; cc < 2; ++cc) s += W2bu_d[t * 2 + cc] * a2bu_d[cc];
    sv2[t] = s;
    sb1[t] = b1bu[t];
  }
  __syncthreads();
  int b = blockIdx.x;
  int j = t & 15;
  if (b < ubBlocks) {
    // ub sharded gather, XCD-pinned: shard s on XCDs {2s, 2s+1}
    int xcd = b & 7;
    int s = xcd >> 1;
    int sub = ((b >> 3) << 1) | (xcd & 1);
    int n = sub * 16 + (t >> 4);
    if (n >= NB) return;
    int base = (n >> 7) * 513 + (n & 127) * 4 + s;
    int beg = rp_ub[base], end = rp_ub[base + 1];
    float adv = ad_b[n];
    float acc[16];
#pragma unroll
    for (int c = 0; c < 16; ++c) acc[c] = 0.f;
    float se = 0.f;
    for (int k = beg + j; k < end; k += 16) {
      int sv = col_ub[k];
      float w = __expf(lrelu(as_u[sv] + adv));
      se += w;
      float row[16];
      load_row16h(hs_u, sv, row);
#pragma unroll
      for (int c = 0; c < 16; ++c) acc[c] += w * row[c];
    }
#pragma unroll
    for (int m = 1; m < 16; m <<= 1) {
      se += __shfl_xor(se, m, 16);
#pragma unroll
      for (int c = 0; c < 16; ++c) acc[c] += __shfl_xor(acc[c], m, 16);
    }
    if (j == 0) {
      float* o = acc_sl + ((size_t)s * NB + n) * 16;
#pragma unroll
      for (int c = 0; c < 16; ++c) o[c] = acc[c];
      se_sl[s * NB + n] = se;
    }
  } else {
    // bu gather + inline layer-2 user transform -> packed pk_u
    int n = (b - ubBlocks) * 16 + (t >> 4);
    if (n >= NU) return;
    int base = (n >> 9) * 513 + (n & 511);
    int beg = rp_bu[base], end = rp_bu[base + 1];
    float adv = ad_u[n];
    float acc[16];
#pragma unroll
    for (int c = 0; c < 16; ++c) acc[c] = 0.f;
    float se = 0.f;
    for (int k = beg + j; k < end; k += 16) {
      int sv = col_bu[k];
      float w = __expf(lrelu(as_b[sv] + adv));
      se += w;
      float row[16];
      load_row16h(hs_b, sv, row);
#pragma unroll
      for (int c = 0; c < 16; ++c) acc[c] += w * row[c];
    }
#pragma unroll
    for (int m = 1; m < 16; m <<= 1) {
      se += __shfl_xor(se, m, 16);
#pragma unroll
      for (int c = 0; c < 16; ++c) acc[c] += __shfl_xor(acc[c], m, 16);
    }
    if (j == 0) {
      float inv = 1.f / (se + 1e-16f);
      float h0 = 0.f, h1 = 0.f, advn = 0.f;
#pragma unroll
      for (int c = 0; c < 16; ++c) {
        float xv = fmaxf(acc[c] * inv + sb1[c], 0.f);
        h0 += xv * sW2[c * 2];
        h1 += xv * sW2[c * 2 + 1];
        advn += xv * sv2[c];
      }
      pk_u[n] = make_float4(h0 * sa2[0] + h1 * sa2[1], h0, h1, advn);
    }
  }
}

// ---------------- finalize badges + inline layer-2 badge transform ----------------
__global__ void k_finL1b(
    const float* __restrict__ acc_sl, const float* __restrict__ se_sl,
    const float* __restrict__ b1ub,
    const float* __restrict__ W2bu_s, const float* __restrict__ a2bu_s,
    const float* __restrict__ W2ub_d, const float* __restrict__ a2ub_d,
    float4* __restrict__ pk_b, int NB) {
  __shared__ float sW2[32], sa2[2], sv2[16], sb1[16];
  int t = threadIdx.x;
  if (t < 32) sW2[t] = W2bu_s[t];
  if (t < 2) sa2[t] = a2bu_s[t];
  if (t < 16) {
    float s = 0.f;
    for (int cc = 0; cc < 2; ++cc) s += W2ub_d[t * 2 + cc] * a2ub_d[cc];
    sv2[t] = s;
    sb1[t] = b1ub[t];
  }
  __syncthreads();
  int n = blockIdx.x * 256 + t;
  if (n >= NB) return;
  float a[16];
#pragma unroll
  for (int c = 0; c < 16; ++c) a[c] = 0.f;
  float se = 0.f;
  for (int s = 0; s < 4; ++s) {
    const float4* p = (const float4*)(acc_sl + ((size_t)s * NB + n) * 16);
    float4 v0 = p[0], v1 = p[1], v2 = p[2], v3 = p[3];
    a[0] += v0.x; a[1] += v0.y; a[2] += v0.z; a[3] += v0.w;
    a[4] += v1.x; a[5] += v1.y; a[6] += v1.z; a[7] += v1.w;
    a[8] += v2.x; a[9] += v2.y; a[10] += v2.z; a[11] += v2.w;
    a[12] += v3.x; a[13] += v3.y; a[14] += v3.z; a[15] += v3.w;
    se += se_sl[s * NB + n];
  }
  float inv = 1.f / (se + 1e-16f);
  float h0 = 0.f, h1 = 0.f, advn = 0.f;
#pragma unroll
  for (int c = 0; c < 16; ++c) {
    float xv = fmaxf(a[c] * inv + sb1[c], 0.f);
    h0 += xv * sW2[c * 2];
    h1 += xv * sW2[c * 2 + 1];
    advn += xv * sv2[c];
  }
  pk_b[n] = make_float4(h0 * sa2[0] + h1 * sa2[1], h0, h1, advn);
}

// ---------------- fused layer-2 output gathers (packed tables) ----------------
__global__ void k_gatherL2(
    const int* __restrict__ rp0, const int* __restrict__ col0,
    const int* __restrict__ rp1, const int* __restrict__ col1,
    const float4* __restrict__ pk_u, const float4* __restrict__ pk_b,
    const float* __restrict__ b2ub, const float* __restrict__ b2bu,
    float* __restrict__ ob, float* __restrict__ ou,
    int NB, int NU, int g0) {
  int blk = blockIdx.x;
  const int *rp, *col; const float4 *pksrc, *pkown; const float* bb; float* out;
  int N, lsh, nsg;
  if (blk < g0) { rp = rp0; col = col0; pksrc = pk_u; pkown = pk_b; bb = b2ub;
                  out = ob; N = NB; lsh = 7; nsg = 4; }
  else { blk -= g0; rp = rp1; col = col1; pksrc = pk_b; pkown = pk_u; bb = b2bu;
         out = ou; N = NU; lsh = 9; nsg = 1; }
  int n = blk * 16 + (threadIdx.x >> 4);
  int j = threadIdx.x & 15;
  if (n >= N) return;
  int base = (n >> lsh) * 513 + (n & ((1 << lsh) - 1)) * nsg;
  int beg = rp[base], end = rp[base + nsg];
  float adv = pkown[n].w;
  float a0 = 0.f, a1 = 0.f, se = 0.f;
  for (int k = beg + j; k < end; k += 16) {
    float4 pv = pksrc[col[k]];
    float w = __expf(lrelu(pv.x + adv));
    se += w;
    a0 += w * pv.y;
    a1 += w * pv.z;
  }
#pragma unroll
  for (int m = 1; m < 16; m <<= 1) {
    se += __shfl_xor(se, m, 16);
    a0 += __shfl_xor(a0, m, 16);
    a1 += __shfl_xor(a1, m, 16);
  }
  if (j == 0) {
    float inv = 1.f / (se + 1e-16f);
    out[(size_t)n * 2] = a0 * inv + bb[0];
    out[(size_t)n * 2 + 1] = a1 * inv + bb[1];
  }
}

extern "C" void kernel_launch(void* const* d_in, const int* in_sizes, int n_in,
                              void* d_out, int out_size, void* d_ws, size_t ws_size,
                              hipStream_t stream) {
  const int NU = 200000, NB = 50000;
  const float* x_user  = (const float*)d_in[0];
  const float* x_badge = (const float*)d_in[1];
  const int* ub_src = (const int*)d_in[2];
  const int* ub_dst = (const int*)d_in[3];
  const int* bu_src = (const int*)d_in[4];
  const int* bu_dst = (const int*)d_in[5];
  const int nE = in_sizes[2];

  const float* W1_ub_s = (const float*)d_in[8];
  const float* W1_ub_d = (const float*)d_in[9];
  const float* a1_ub_s = (const float*)d_in[10];
  const float* a1_ub_d = (const float*)d_in[11];
  const float* b1_ub   = (const float*)d_in[12];
  const float* W2_ub_s = (const float*)d_in[13];
  const float* W2_ub_d = (const float*)d_in[14];
  const float* a2_ub_s = (const float*)d_in[15];
  const float* a2_ub_d = (const float*)d_in[16];
  const float* b2_ub   = (const float*)d_in[17];
  const float* W1_bu_s = (const float*)d_in[18];
  const float* W1_bu_d = (const float*)d_in[19];
  const float* a1_bu_s = (const float*)d_in[20];
  const float* a1_bu_d = (const float*)d_in[21];
  const float* b1_bu   = (const float*)d_in[22];
  const float* W2_bu_s = (const float*)d_in[23];
  const float* W2_bu_d = (const float*)d_in[24];
  const float* a2_bu_s = (const float*)d_in[25];
  const float* a2_bu_d = (const float*)d_in[26];
  const float* b2_bu   = (const float*)d_in[27];

  const int pblocks = (nE + PART_PER - 1) / PART_PER;
  const int gNU = (NU + 255) / 256;        // 782
  const int gNB = (NB + 255) / 256;        // 196

  // ---- workspace carve-up ----
  char* wsb = (char*)d_ws;
  size_t off = 0;
  auto ialloc = [&](size_t n) { int* p = (int*)(wsb + off); off += n * 4; return p; };
  int* rp2_ub = ialloc((size_t)NHALF * 513);
  int* rp2_bu = ialloc((size_t)NHALF * 513);
  int* bcnt   = ialloc(512);
  int* col_ub = ialloc((size_t)NHALF * CAPH);
  int* col_bu = ialloc((size_t)NHALF * CAPH);
  off = (off + 15) & ~(size_t)15;
  const size_t partBytes = (size_t)2 * NBC * CAPC * 4;           // 42.45 MB
  const size_t nodeBytes = (size_t)NU * 32 + (size_t)NB * 32 +   // hs fp16 + pk f4
                           (size_t)(NU + NB) * 8 + 1024;         // as/ad pairs
  // fused layout needs part + nodes disjoint (nodes written while part live)
  bool fused = ws_size >= off + partBytes + nodeBytes + 4096;
  char* partBase = wsb + off;
  char* nodeBase = fused ? (partBase + partBytes) : partBase;    // fallback: overlay
  unsigned* part0 = (unsigned*)partBase;
  unsigned* part1 = part0 + (size_t)NBC * CAPC;
  size_t poff = 0;
  auto falloc = [&](size_t n) { float* p = (float*)(nodeBase + poff); poff += n * 4; return p; };
  auto halloc = [&](size_t n) { __half* p = (__half*)(nodeBase + poff); poff += n * 2; return p; };
  __half* hs_u1 = halloc((size_t)NU * 16);
  __half* hs_b1 = halloc((size_t)NB * 16);
  float* as_u1  = falloc(NU);
  float* ad_u1  = falloc(NU);
  float* as_b1  = falloc(NB);
  float* ad_b1  = falloc(NB);
  poff = (poff + 15) & ~(size_t)15;
  float4* pk_u  = (float4*)(nodeBase + poff); poff += (size_t)NU * 16;
  float4* pk_b  = (float4*)(nodeBase + poff); poff += (size_t)NB * 16;
  // acc slices: overlay part (dead by megaL1) when fused, else after nodes
  char* accBase = fused ? partBase : (nodeBase + ((poff + 15) & ~(size_t)15));
  float* acc_sl = (float*)accBase;
  float* se_sl  = (float*)(accBase + (size_t)4 * NB * 16 * 4);

  float* ou = (float*)d_out;                   // [NU,2]
  float* ob = (float*)d_out + (size_t)NU * 2;  // [NB,2]

  const int ubBlocks = ((NB / 16 + 1) / 2 + 1) * 8;
  const int buBlocks = (NU * 16 + 255) / 256;
  const int g0 = (NB * 16 + 255) / 256;

  hipMemsetAsync(bcnt, 0, 512 * 4, stream);
  if (fused) {
    k_stageA<<<dim3(2 * pblocks + gNU + gNB), dim3(256), 0, stream>>>(
        ub_src, ub_dst, bu_src, bu_dst, nE, pblocks, part0, part1, bcnt,
        x_user, x_badge, W1_ub_s, a1_ub_s, W1_bu_d, a1_bu_d,
        W1_bu_s, a1_bu_s, W1_ub_d, a1_ub_d,
        hs_u1, as_u1, ad_u1, hs_b1, as_b1, ad_b1, NU, NB, gNU, 2 * pblocks);
    k_sort2_both<<<dim3(2 * NHALF), dim3(512), 0, stream>>>(
        part0, part1, bcnt, col_ub, col_bu, rp2_ub, rp2_bu);
  } else {
    // fallback: partition alone, then sort2, then nodes (overlaying part)
    k_stageA<<<dim3(2 * pblocks), dim3(256), 0, stream>>>(
        ub_src, ub_dst, bu_src, bu_dst, nE, pblocks, part0, part1, bcnt,
        x_user, x_badge, W1_ub_s, a1_ub_s, W1_bu_d, a1_bu_d,
        W1_bu_s, a1_bu_s, W1_ub_d, a1_ub_d,
        hs_u1, as_u1, ad_u1, hs_b1, as_b1, ad_b1, NU, NB, gNU, 2 * pblocks);
    k_sort2_both<<<dim3(2 * NHALF), dim3(512), 0, stream>>>(
        part0, part1, bcnt, col_ub, col_bu, rp2_ub, rp2_bu);
    k_stageA<<<dim3(gNU + gNB), dim3(256), 0, stream>>>(
        ub_src, ub_dst, bu_src, bu_dst, nE, pblocks, part0, part1, bcnt,
        x_user, x_badge, W1_ub_s, a1_ub_s, W1_bu_d, a1_bu_d,
        W1_bu_s, a1_bu_s, W1_ub_d, a1_ub_d,
        hs_u1, as_u1, ad_u1, hs_b1, as_b1, ad_b1, NU, NB, gNU, 0);
  }
  k_megaL1<<<dim3(ubBlocks + buBlocks), dim3(256), 0, stream>>>(
      rp2_ub, col_ub, as_u1, ad_b1, hs_u1, acc_sl, se_sl,
      rp2_bu, col_bu, as_b1, ad_u1, hs_b1,
      b1_bu, W2_ub_s, a2_ub_s, W2_bu_d, a2_bu_d,
      pk_u, NB, NU, ubBlocks);
  k_finL1b<<<dim3(gNB), dim3(256), 0, stream>>>(
      acc_sl, se_sl, b1_ub, W2_bu_s, a2_bu_s, W2_ub_d, a2_ub_d, pk_b, NB);
  k_gatherL2<<<dim3(g0 + buBlocks), dim3(256), 0, stream>>>(
      rp2_ub, col_ub, rp2_bu, col_bu, pk_u, pk_b, b2_ub, b2_bu, ob, ou, NB, NU, g0);
}

// Round 13
// 466.694 us; speedup vs baseline: 1.4817x; 1.1839x over previous
//
#include <hip/hip_runtime.h>
#include <hip/hip_fp16.h>
#include <math.h>

// HeteroGNN: 2-layer bipartite single-head GAT (users<->badges).
// R13 (from R12 @552us; stageA 143us = partition 125 + nodes 18, NO overlap
// because block order serialized them):
//   - stageA block-index INTERLEAVE (2 partition : 1 node, period 3) so both
//     kinds are co-resident; node VALU work fills partition latency bubbles.
//   - int4/uint4 vectorized edge-stream reads in partition hist+scatter and
//     sort2's two scan passes (4x fewer mem instructions, 16B per load).
// Everything else identical to R12 (packed-float4 L2 gather, XCD-pinned
// sharded megaL1, inline L2 node transforms).

#define NEG_SLOPE 0.2f
#define PART_PER 4880
#define NBC 196
#define CAPC 27072
#define NHALF 392
#define CAPH 13824
#define SHARD_DIV 50000

__device__ __forceinline__ float lrelu(float x) { return x > 0.f ? x : NEG_SLOPE * x; }

// ---------------- stage A: coarse partition (both graphs) + L1 node transforms ----------------
__global__ void k_stageA(
    const int* __restrict__ src0, const int* __restrict__ dst0,
    const int* __restrict__ src1, const int* __restrict__ dst1,
    int nE, int pblocks, unsigned* __restrict__ part0, unsigned* __restrict__ part1,
    int* __restrict__ bcnt,
    const float* __restrict__ xu, const float* __restrict__ xb,
    const float* __restrict__ Wub_s, const float* __restrict__ aub_s,
    const float* __restrict__ Wbu_d, const float* __restrict__ abu_d,
    const float* __restrict__ Wbu_s, const float* __restrict__ abu_s,
    const float* __restrict__ Wub_d, const float* __restrict__ aub_d,
    __half* __restrict__ hs_u, float* __restrict__ as_u, float* __restrict__ ad_u,
    __half* __restrict__ hs_b, float* __restrict__ as_b, float* __restrict__ ad_b,
    int NU, int NB, int gNU, int partBlocks, int nodeBlocks) {
  union Sm {
    struct { unsigned s_sorted[PART_PER]; int h[257]; int ps[256]; int resb[256]; int cur[256]; } p;
    struct { float sW[64 * 16]; float sa[16]; float sv[64]; } n;
  };
  __shared__ Sm sm;
  int t = threadIdx.x;
  // ---- interleave mapping: 2 partition blocks : 1 node block ----
  int b = blockIdx.x;
  int k = min(nodeBlocks, partBlocks / 2);
  int inter = 3 * k;
  int partIdx = -1, nodeIdx = -1;
  if (b < inter) {
    if ((b % 3) == 2) nodeIdx = b / 3;
    else partIdx = (b / 3) * 2 + (b % 3);
  } else {
    int rem = b - inter;
    int ptail = partBlocks - 2 * k;
    if (rem < ptail) partIdx = 2 * k + rem;
    else nodeIdx = k + (rem - ptail);
  }
  if (partIdx >= 0) {
    // ===== partition branch =====
    int gb = partIdx;
    const int* src; const int* dst; unsigned* part; int* bc; int shift; int mask;
    if (gb < pblocks) { src = src0; dst = dst0; part = part0; bc = bcnt; shift = 8; mask = 255; }
    else { gb -= pblocks; src = src1; dst = dst1; part = part1; bc = bcnt + 256; shift = 10; mask = 1023; }
    int per = (nE + pblocks - 1) / pblocks;
    int beg = gb * per;
    int end = min(beg + per, nE);
    int cnt = end - beg;
    int cnt4 = cnt & ~3;
    sm.p.h[t] = 0;
    __syncthreads();
    // hist: int4 loads (beg 16B-aligned: per % 4 == 0)
    for (int i = beg + t * 4; i + 3 < end; i += 1024) {
      int4 d4 = *(const int4*)(dst + i);
      atomicAdd(&sm.p.h[d4.x >> shift], 1);
      atomicAdd(&sm.p.h[d4.y >> shift], 1);
      atomicAdd(&sm.p.h[d4.z >> shift], 1);
      atomicAdd(&sm.p.h[d4.w >> shift], 1);
    }
    for (int i = beg + cnt4 + t; i < end; i += 256) atomicAdd(&sm.p.h[dst[i] >> shift], 1);
    __syncthreads();
    int v = sm.p.h[t];
    sm.p.ps[t] = v;
    __syncthreads();
    for (int off = 1; off < 256; off <<= 1) {
      int u = (t >= off) ? sm.p.ps[t - off] : 0;
      __syncthreads();
      sm.p.ps[t] += u;
      __syncthreads();
    }
    int excl = sm.p.ps[t] - v;
    sm.p.resb[t] = (t < NBC && v > 0) ? atomicAdd(&bc[t], v) : 0;
    __syncthreads();
    sm.p.h[t] = excl;
    sm.p.cur[t] = excl;
    if (t == 255) sm.p.h[256] = excl + v;
    __syncthreads();
    // scatter: int4 loads of dst+src
    for (int i = beg + t * 4; i + 3 < end; i += 1024) {
      int4 d4 = *(const int4*)(dst + i);
      int4 s4 = *(const int4*)(src + i);
      int r;
      r = atomicAdd(&sm.p.cur[d4.x >> shift], 1);
      sm.p.s_sorted[r] = ((unsigned)(d4.x & mask) << 18) | (unsigned)s4.x;
      r = atomicAdd(&sm.p.cur[d4.y >> shift], 1);
      sm.p.s_sorted[r] = ((unsigned)(d4.y & mask) << 18) | (unsigned)s4.y;
      r = atomicAdd(&sm.p.cur[d4.z >> shift], 1);
      sm.p.s_sorted[r] = ((unsigned)(d4.z & mask) << 18) | (unsigned)s4.z;
      r = atomicAdd(&sm.p.cur[d4.w >> shift], 1);
      sm.p.s_sorted[r] = ((unsigned)(d4.w & mask) << 18) | (unsigned)s4.w;
    }
    for (int i = beg + cnt4 + t; i < end; i += 256) {
      int d = dst[i];
      int r = atomicAdd(&sm.p.cur[d >> shift], 1);
      sm.p.s_sorted[r] = ((unsigned)(d & mask) << 18) | (unsigned)src[i];
    }
    __syncthreads();
    // flush: 4 concurrent binary-search chains per thread (ILP)
    for (int i = t; i < cnt; i += 1024) {
      int i1 = i + 256, i2 = i + 512, i3 = i + 768;
      int lo0 = 0, lo1 = 0, lo2 = 0, lo3 = 0;
      int hi0 = 256, hi1 = 256, hi2 = 256, hi3 = 256;
#pragma unroll
      for (int s = 0; s < 8; ++s) {
        int m0 = (lo0 + hi0) >> 1; if (sm.p.h[m0] <= i)  lo0 = m0; else hi0 = m0;
        int m1 = (lo1 + hi1) >> 1; if (sm.p.h[m1] <= i1) lo1 = m1; else hi1 = m1;
        int m2 = (lo2 + hi2) >> 1; if (sm.p.h[m2] <= i2) lo2 = m2; else hi2 = m2;
        int m3 = (lo3 + hi3) >> 1; if (sm.p.h[m3] <= i3) lo3 = m3; else hi3 = m3;
      }
      { int p = sm.p.resb[lo0] + (i - sm.p.h[lo0]);
        if (p < CAPC) part[(size_t)lo0 * CAPC + p] = sm.p.s_sorted[i]; }
      if (i1 < cnt) { int p = sm.p.resb[lo1] + (i1 - sm.p.h[lo1]);
        if (p < CAPC) part[(size_t)lo1 * CAPC + p] = sm.p.s_sorted[i1]; }
      if (i2 < cnt) { int p = sm.p.resb[lo2] + (i2 - sm.p.h[lo2]);
        if (p < CAPC) part[(size_t)lo2 * CAPC + p] = sm.p.s_sorted[i2]; }
      if (i3 < cnt) { int p = sm.p.resb[lo3] + (i3 - sm.p.h[lo3]);
        if (p < CAPC) part[(size_t)lo3 * CAPC + p] = sm.p.s_sorted[i3]; }
    }
    return;
  }
  // ===== nodes branch =====
  int blk = nodeIdx;
  bool us = blk < gNU;
  const float* x  = us ? xu : xb;
  const float* Ws = us ? Wub_s : Wbu_s;
  const float* As = us ? aub_s : abu_s;
  const float* Wd = us ? Wbu_d : Wub_d;
  const float* Ad = us ? abu_d : aub_d;
  __half* hs = us ? hs_u : hs_b;
  float* als = us ? as_u : as_b;
  float* ald = us ? ad_u : ad_b;
  int N = us ? NU : NB;
  for (int i = t; i < 64 * 16; i += 256) sm.n.sW[i] = Ws[i];
  if (t < 16) sm.n.sa[t] = As[t];
  if (t < 64) {
    float s = 0.f;
    for (int c = 0; c < 16; ++c) s += Wd[t * 16 + c] * Ad[c];
    sm.n.sv[t] = s;
  }
  __syncthreads();
  int n = (us ? blk : blk - gNU) * 256 + t;
  if (n >= N) return;
  float acc[16];
#pragma unroll
  for (int c = 0; c < 16; ++c) acc[c] = 0.f;
  float ad = 0.f;
  const float4* xr4 = (const float4*)(x + (size_t)n * 64);
#pragma unroll 4
  for (int f4 = 0; f4 < 16; ++f4) {
    float4 xv4 = xr4[f4];
    float xv[4] = {xv4.x, xv4.y, xv4.z, xv4.w};
#pragma unroll
    for (int q = 0; q < 4; ++q) {
      int f = f4 * 4 + q;
#pragma unroll
      for (int c = 0; c < 16; ++c) acc[c] += xv[q] * sm.n.sW[f * 16 + c];
      ad += xv[q] * sm.n.sv[f];
    }
  }
  float al = 0.f;
#pragma unroll
  for (int c = 0; c < 16; ++c) {
    hs[(size_t)n * 16 + c] = __float2half(acc[c]);
    al += acc[c] * sm.n.sa[c];
  }
  als[n] = al;
  ald[n] = ad;
}

// ---------------- CSR stage 2: half-bucket sort, both graphs ----------------
__global__ void k_sort2_both(const unsigned* __restrict__ part0,
                             const unsigned* __restrict__ part1,
                             const int* __restrict__ bcnt,
                             int* __restrict__ col0, int* __restrict__ col1,
                             int* __restrict__ rp0, int* __restrict__ rp1) {
  __shared__ unsigned s_sorted[CAPH];
  __shared__ int hist[512];
  __shared__ int ps[512];
  __shared__ int cur[512];
  __shared__ int s_tot;
  int bb = blockIdx.x;
  const unsigned* part; const int* bc; int* col; int* rp;
  int hsh, hmask, ns, sdiv;
  if (bb < NHALF) { part = part0; bc = bcnt; col = col0; rp = rp0;
                    hsh = 7; hmask = 127; ns = 4; sdiv = SHARD_DIV; }
  else { bb -= NHALF; part = part1; bc = bcnt + 256; col = col1; rp = rp1;
         hsh = 9; hmask = 511; ns = 1; sdiv = 1 << 30; }
  int t = threadIdx.x;
  int f = bb >> 1;
  int half = bb & 1;
  int cnt = min(bc[f], CAPC);
  int cnt4 = cnt & ~3;
  int slot = bb * CAPH;
  const unsigned* pp = part + (size_t)f * CAPC;
  hist[t] = 0;
  __syncthreads();
  for (int i = t * 4; i + 3 < cnt; i += 2048) {
    uint4 e4 = *(const uint4*)(pp + i);
    unsigned ee[4] = {e4.x, e4.y, e4.z, e4.w};
#pragma unroll
    for (int q = 0; q < 4; ++q) {
      int dl = (int)(ee[q] >> 18);
      if ((dl >> hsh) == half) {
        int sv = (int)(ee[q] & 0x3FFFFu);
        int bin = (ns == 4) ? ((dl & hmask) << 2) + sv / sdiv : (dl & hmask);
        atomicAdd(&hist[bin], 1);
      }
    }
  }
  for (int i = cnt4 + t; i < cnt; i += 512) {
    unsigned e = pp[i];
    int dl = (int)(e >> 18);
    if ((dl >> hsh) == half) {
      int sv = (int)(e & 0x3FFFFu);
      int bin = (ns == 4) ? ((dl & hmask) << 2) + sv / sdiv : (dl & hmask);
      atomicAdd(&hist[bin], 1);
    }
  }
  __syncthreads();
  int v = hist[t];
  ps[t] = v;
  __syncthreads();
  for (int off = 1; off < 512; off <<= 1) {
    int u = (t >= off) ? ps[t - off] : 0;
    __syncthreads();
    ps[t] += u;
    __syncthreads();
  }
  int excl = ps[t] - v;
  rp[bb * 513 + t] = slot + excl;
  if (t == 511) {
    int tot = min(ps[511], CAPH);
    rp[bb * 513 + 512] = slot + tot;
    s_tot = tot;
  }
  cur[t] = excl;
  __syncthreads();
  for (int i = t * 4; i + 3 < cnt; i += 2048) {
    uint4 e4 = *(const uint4*)(pp + i);
    unsigned ee[4] = {e4.x, e4.y, e4.z, e4.w};
#pragma unroll
    for (int q = 0; q < 4; ++q) {
      int dl = (int)(ee[q] >> 18);
      if ((dl >> hsh) == half) {
        int sv = (int)(ee[q] & 0x3FFFFu);
        int bin = (ns == 4) ? ((dl & hmask) << 2) + sv / sdiv : (dl & hmask);
        int r = atomicAdd(&cur[bin], 1);
        if (r < CAPH) s_sorted[r] = (unsigned)sv;
      }
    }
  }
  for (int i = cnt4 + t; i < cnt; i += 512) {
    unsigned e = pp[i];
    int dl = (int)(e >> 18);
    if ((dl >> hsh) == half) {
      int sv = (int)(e & 0x3FFFFu);
      int bin = (ns == 4) ? ((dl & hmask) << 2) + sv / sdiv : (dl & hmask);
      int r = atomicAdd(&cur[bin], 1);
      if (r < CAPH) s_sorted[r] = (unsigned)sv;
    }
  }
  __syncthreads();
  int tot = s_tot;
  for (int i = t; i < tot; i += 512) col[slot + i] = (int)s_sorted[i];
}

// ---------------- mega layer-1 gather ----------------
__device__ __forceinline__ void load_row16h(const __half* __restrict__ hs, int s,
                                            float (&row)[16]) {
  union { uint4 v[2]; __half h[16]; } buf;
  const uint4* hv = (const uint4*)(hs + (size_t)s * 16);
  buf.v[0] = hv[0];
  buf.v[1] = hv[1];
#pragma unroll
  for (int c = 0; c < 16; ++c) row[c] = __half2float(buf.h[c]);
}

__global__ void k_megaL1(
    const int* __restrict__ rp_ub, const int* __restrict__ col_ub,
    const float* __restrict__ as_u, const float* __restrict__ ad_b,
    const __half* __restrict__ hs_u,
    float* __restrict__ acc_sl, float* __restrict__ se_sl,
    const int* __restrict__ rp_bu, const int* __restrict__ col_bu,
    const float* __restrict__ as_b, const float* __restrict__ ad_u,
    const __half* __restrict__ hs_b,
    const float* __restrict__ b1bu,
    const float* __restrict__ W2ub_s, const float* __restrict__ a2ub_s,
    const float* __restrict__ W2bu_d, const float* __restrict__ a2bu_d,
    float4* __restrict__ pk_u, int NB, int NU, int ubBlocks) {
  __shared__ float sW2[32], sa2[2], sv2[16], sb1[16];
  int t = threadIdx.x;
  if (t < 32) sW2[t] = W2ub_s[t];
  if (t < 2) sa2[t] = a2ub_s[t];
  if (t < 16) {
    float s = 0.f;
    for (int cc = 0; cc < 2; ++cc) s += W2bu_d[t * 2 + cc] * a2bu_d[cc];
    sv2[t] = s;
    sb1[t] = b1bu[t];
  }
  __syncthreads();
  int b = blockIdx.x;
  int j = t & 15;
  if (b < ubBlocks) {
    int xcd = b & 7;
    int s = xcd >> 1;
    int sub = ((b >> 3) << 1) | (xcd & 1);
    int n = sub * 16 + (t >> 4);
    if (n >= NB) return;
    int base = (n >> 7) * 513 + (n & 127) * 4 + s;
    int beg = rp_ub[base], end = rp_ub[base + 1];
    float adv = ad_b[n];
    float acc[16];
#pragma unroll
    for (int c = 0; c < 16; ++c) acc[c] = 0.f;
    float se = 0.f;
    for (int k = beg + j; k < end; k += 16) {
      int sv = col_ub[k];
      float w = __expf(lrelu(as_u[sv] + adv));
      se += w;
      float row[16];
      load_row16h(hs_u, sv, row);
#pragma unroll
      for (int c = 0; c < 16; ++c) acc[c] += w * row[c];
    }
#pragma unroll
    for (int m = 1; m < 16; m <<= 1) {
      se += __shfl_xor(se, m, 16);
#pragma unroll
      for (int c = 0; c < 16; ++c) acc[c] += __shfl_xor(acc[c], m, 16);
    }
    if (j == 0) {
      float* o = acc_sl + ((size_t)s * NB + n) * 16;
#pragma unroll
      for (int c = 0; c < 16; ++c) o[c] = acc[c];
      se_sl[s * NB + n] = se;
    }
  } else {
    int n = (b - ubBlocks) * 16 + (t >> 4);
    if (n >= NU) return;
    int base = (n >> 9) * 513 + (n & 511);
    int beg = rp_bu[base], end = rp_bu[base + 1];
    float adv = ad_u[n];
    float acc[16];
#pragma unroll
    for (int c = 0; c < 16; ++c) acc[c] = 0.f;
    float se = 0.f;
    for (int k = beg + j; k < end; k += 16) {
      int sv = col_bu[k];
      float w = __expf(lrelu(as_b[sv] + adv));
      se += w;
      float row[16];
      load_row16h(hs_b, sv, row);
#pragma unroll
      for (int c = 0; c < 16; ++c) acc[c] += w * row[c];
    }
#pragma unroll
    for (int m = 1; m < 16; m <<= 1) {
      se += __shfl_xor(se, m, 16);
#pragma unroll
      for (int c = 0; c < 16; ++c) acc[c] += __shfl_xor(acc[c], m, 16);
    }
    if (j == 0) {
      float inv = 1.f / (se + 1e-16f);
      float h0 = 0.f, h1 = 0.f, advn = 0.f;
#pragma unroll
      for (int c = 0; c < 16; ++c) {
        float xv = fmaxf(acc[c] * inv + sb1[c], 0.f);
        h0 += xv * sW2[c * 2];
        h1 += xv * sW2[c * 2 + 1];
        advn += xv * sv2[c];
      }
      pk_u[n] = make_float4(h0 * sa2[0] + h1 * sa2[1], h0, h1, advn);
    }
  }
}

// ---------------- finalize badges + inline layer-2 badge transform ----------------
__global__ void k_finL1b(
    const float* __restrict__ acc_sl, const float* __restrict__ se_sl,
    const float* __restrict__ b1ub,
    const float* __restrict__ W2bu_s, const float* __restrict__ a2bu_s,
    const float* __restrict__ W2ub_d, const float* __restrict__ a2ub_d,
    float4* __restrict__ pk_b, int NB) {
  __shared__ float sW2[32], sa2[2], sv2[16], sb1[16];
  int t = threadIdx.x;
  if (t < 32) sW2[t] = W2bu_s[t];
  if (t < 2) sa2[t] = a2bu_s[t];
  if (t < 16) {
    float s = 0.f;
    for (int cc = 0; cc < 2; ++cc) s += W2ub_d[t * 2 + cc] * a2ub_d[cc];
    sv2[t] = s;
    sb1[t] = b1ub[t];
  }
  __syncthreads();
  int n = blockIdx.x * 256 + t;
  if (n >= NB) return;
  float a[16];
#pragma unroll
  for (int c = 0; c < 16; ++c) a[c] = 0.f;
  float se = 0.f;
  for (int s = 0; s < 4; ++s) {
    const float4* p = (const float4*)(acc_sl + ((size_t)s * NB + n) * 16);
    float4 v0 = p[0], v1 = p[1], v2 = p[2], v3 = p[3];
    a[0] += v0.x; a[1] += v0.y; a[2] += v0.z; a[3] += v0.w;
    a[4] += v1.x; a[5] += v1.y; a[6] += v1.z; a[7] += v1.w;
    a[8] += v2.x; a[9] += v2.y; a[10] += v2.z; a[11] += v2.w;
    a[12] += v3.x; a[13] += v3.y; a[14] += v3.z; a[15] += v3.w;
    se += se_sl[s * NB + n];
  }
  float inv = 1.f / (se + 1e-16f);
  float h0 = 0.f, h1 = 0.f, advn = 0.f;
#pragma unroll
  for (int c = 0; c < 16; ++c) {
    float xv = fmaxf(a[c] * inv + sb1[c], 0.f);
    h0 += xv * sW2[c * 2];
    h1 += xv * sW2[c * 2 + 1];
    advn += xv * sv2[c];
  }
  pk_b[n] = make_float4(h0 * sa2[0] + h1 * sa2[1], h0, h1, advn);
}

// ---------------- fused layer-2 output gathers (packed tables) ----------------
__global__ void k_gatherL2(
    const int* __restrict__ rp0, const int* __restrict__ col0,
    const int* __restrict__ rp1, const int* __restrict__ col1,
    const float4* __restrict__ pk_u, const float4* __restrict__ pk_b,
    const float* __restrict__ b2ub, const float* __restrict__ b2bu,
    float* __restrict__ ob, float* __restrict__ ou,
    int NB, int NU, int g0) {
  int blk = blockIdx.x;
  const int *rp, *col; const float4 *pksrc, *pkown; const float* bb; float* out;
  int N, lsh, nsg;
  if (blk < g0) { rp = rp0; col = col0; pksrc = pk_u; pkown = pk_b; bb = b2ub;
                  out = ob; N = NB; lsh = 7; nsg = 4; }
  else { blk -= g0; rp = rp1; col = col1; pksrc = pk_b; pkown = pk_u; bb = b2bu;
         out = ou; N = NU; lsh = 9; nsg = 1; }
  int n = blk * 16 + (threadIdx.x >> 4);
  int j = threadIdx.x & 15;
  if (n >= N) return;
  int base = (n >> lsh) * 513 + (n & ((1 << lsh) - 1)) * nsg;
  int beg = rp[base], end = rp[base + nsg];
  float adv = pkown[n].w;
  float a0 = 0.f, a1 = 0.f, se = 0.f;
  for (int k = beg + j; k < end; k += 16) {
    float4 pv = pksrc[col[k]];
    float w = __expf(lrelu(pv.x + adv));
    se += w;
    a0 += w * pv.y;
    a1 += w * pv.z;
  }
#pragma unroll
  for (int m = 1; m < 16; m <<= 1) {
    se += __shfl_xor(se, m, 16);
    a0 += __shfl_xor(a0, m, 16);
    a1 += __shfl_xor(a1, m, 16);
  }
  if (j == 0) {
    float inv = 1.f / (se + 1e-16f);
    out[(size_t)n * 2] = a0 * inv + bb[0];
    out[(size_t)n * 2 + 1] = a1 * inv + bb[1];
  }
}

extern "C" void kernel_launch(void* const* d_in, const int* in_sizes, int n_in,
                              void* d_out, int out_size, void* d_ws, size_t ws_size,
                              hipStream_t stream) {
  const int NU = 200000, NB = 50000;
  const float* x_user  = (const float*)d_in[0];
  const float* x_badge = (const float*)d_in[1];
  const int* ub_src = (const int*)d_in[2];
  const int* ub_dst = (const int*)d_in[3];
  const int* bu_src = (const int*)d_in[4];
  const int* bu_dst = (const int*)d_in[5];
  const int nE = in_sizes[2];

  const float* W1_ub_s = (const float*)d_in[8];
  const float* W1_ub_d = (const float*)d_in[9];
  const float* a1_ub_s = (const float*)d_in[10];
  const float* a1_ub_d = (const float*)d_in[11];
  const float* b1_ub   = (const float*)d_in[12];
  const float* W2_ub_s = (const float*)d_in[13];
  const float* W2_ub_d = (const float*)d_in[14];
  const float* a2_ub_s = (const float*)d_in[15];
  const float* a2_ub_d = (const float*)d_in[16];
  const float* b2_ub   = (const float*)d_in[17];
  const float* W1_bu_s = (const float*)d_in[18];
  const float* W1_bu_d = (const float*)d_in[19];
  const float* a1_bu_s = (const float*)d_in[20];
  const float* a1_bu_d = (const float*)d_in[21];
  const float* b1_bu   = (const float*)d_in[22];
  const float* W2_bu_s = (const float*)d_in[23];
  const float* W2_bu_d = (const float*)d_in[24];
  const float* a2_bu_s = (const float*)d_in[25];
  const float* a2_bu_d = (const float*)d_in[26];
  const float* b2_bu   = (const float*)d_in[27];

  const int pblocks = (nE + PART_PER - 1) / PART_PER;
  const int gNU = (NU + 255) / 256;        // 782
  const int gNB = (NB + 255) / 256;        // 196

  // ---- workspace carve-up ----
  char* wsb = (char*)d_ws;
  size_t off = 0;
  auto ialloc = [&](size_t n) { int* p = (int*)(wsb + off); off += n * 4; return p; };
  int* rp2_ub = ialloc((size_t)NHALF * 513);
  int* rp2_bu = ialloc((size_t)NHALF * 513);
  int* bcnt   = ialloc(512);
  int* col_ub = ialloc((size_t)NHALF * CAPH);
  int* col_bu = ialloc((size_t)NHALF * CAPH);
  off = (off + 15) & ~(size_t)15;
  const size_t partBytes = (size_t)2 * NBC * CAPC * 4;
  const size_t nodeBytes = (size_t)NU * 32 + (size_t)NB * 32 +
                           (size_t)(NU + NB) * 8 + 1024;
  bool fused = ws_size >= off + partBytes + nodeBytes + 4096;
  char* partBase = wsb + off;
  char* nodeBase = fused ? (partBase + partBytes) : partBase;
  unsigned* part0 = (unsigned*)partBase;
  unsigned* part1 = part0 + (size_t)NBC * CAPC;
  size_t poff = 0;
  auto falloc = [&](size_t n) { float* p = (float*)(nodeBase + poff); poff += n * 4; return p; };
  auto halloc = [&](size_t n) { __half* p = (__half*)(nodeBase + poff); poff += n * 2; return p; };
  __half* hs_u1 = halloc((size_t)NU * 16);
  __half* hs_b1 = halloc((size_t)NB * 16);
  float* as_u1  = falloc(NU);
  float* ad_u1  = falloc(NU);
  float* as_b1  = falloc(NB);
  float* ad_b1  = falloc(NB);
  poff = (poff + 15) & ~(size_t)15;
  float4* pk_u  = (float4*)(nodeBase + poff); poff += (size_t)NU * 16;
  float4* pk_b  = (float4*)(nodeBase + poff); poff += (size_t)NB * 16;
  char* accBase = fused ? partBase : (nodeBase + ((poff + 15) & ~(size_t)15));
  float* acc_sl = (float*)accBase;
  float* se_sl  = (float*)(accBase + (size_t)4 * NB * 16 * 4);

  float* ou = (float*)d_out;                   // [NU,2]
  float* ob = (float*)d_out + (size_t)NU * 2;  // [NB,2]

  const int ubBlocks = ((NB / 16 + 1) / 2 + 1) * 8;
  const int buBlocks = (NU * 16 + 255) / 256;
  const int g0 = (NB * 16 + 255) / 256;

  hipMemsetAsync(bcnt, 0, 512 * 4, stream);
  if (fused) {
    k_stageA<<<dim3(2 * pblocks + gNU + gNB), dim3(256), 0, stream>>>(
        ub_src, ub_dst, bu_src, bu_dst, nE, pblocks, part0, part1, bcnt,
        x_user, x_badge, W1_ub_s, a1_ub_s, W1_bu_d, a1_bu_d,
        W1_bu_s, a1_bu_s, W1_ub_d, a1_ub_d,
        hs_u1, as_u1, ad_u1, hs_b1, as_b1, ad_b1, NU, NB, gNU,
        2 * pblocks, gNU + gNB);
    k_sort2_both<<<dim3(2 * NHALF), dim3(512), 0, stream>>>(
        part0, part1, bcnt, col_ub, col_bu, rp2_ub, rp2_bu);
  } else {
    k_stageA<<<dim3(2 * pblocks), dim3(256), 0, stream>>>(
        ub_src, ub_dst, bu_src, bu_dst, nE, pblocks, part0, part1, bcnt,
        x_user, x_badge, W1_ub_s, a1_ub_s, W1_bu_d, a1_bu_d,
        W1_bu_s, a1_bu_s, W1_ub_d, a1_ub_d,
        hs_u1, as_u1, ad_u1, hs_b1, as_b1, ad_b1, NU, NB, gNU,
        2 * pblocks, 0);
    k_sort2_both<<<dim3(2 * NHALF), dim3(512), 0, stream>>>(
        part0, part1, bcnt, col_ub, col_bu, rp2_ub, rp2_bu);
    k_stageA<<<dim3(gNU + gNB), dim3(256), 0, stream>>>(
        ub_src, ub_dst, bu_src, bu_dst, nE, pblocks, part0, part1, bcnt,
        x_user, x_badge, W1_ub_s, a1_ub_s, W1_bu_d, a1_bu_d,
        W1_bu_s, a1_bu_s, W1_ub_d, a1_ub_d,
        hs_u1, as_u1, ad_u1, hs_b1, as_b1, ad_b1, NU, NB, gNU,
        0, gNU + gNB);
  }
  k_megaL1<<<dim3(ubBlocks + buBlocks), dim3(256), 0, stream>>>(
      rp2_ub, col_ub, as_u1, ad_b1, hs_u1, acc_sl, se_sl,
      rp2_bu, col_bu, as_b1, ad_u1, hs_b1,
      b1_bu, W2_ub_s, a2_ub_s, W2_bu_d, a2_bu_d,
      pk_u, NB, NU, ubBlocks);
  k_finL1b<<<dim3(gNB), dim3(256), 0, stream>>>(
      acc_sl, se_sl, b1_ub, W2_bu_s, a2_bu_s, W2_ub_d, a2_ub_d, pk_b, NB);
  k_gatherL2<<<dim3(g0 + buBlocks), dim3(256), 0, stream>>>(
      rp2_ub, col_ub, rp2_bu, col_bu, pk_u, pk_b, b2_ub, b2_bu, ob, ou, NB, NU, g0);
}